// Round 1
// baseline (439.985 us; speedup 1.0000x reference)
//
#include <hip/hip_runtime.h>
#include <hip/hip_bf16.h>
#include <math.h>

// Problem constants
#define B_   2
#define S_   2048
#define DM   768
#define H_   16      // N_QK
#define E_   16      // D_QK
#define C_   256     // N_OV
#define VKV_ 16
#define SK   2064    // S_ + VKV_

// Workspace layout (floats). Z aliases P (P is dead after rope_scatter).
#define OFF_P 0
#define OFF_Z 0
#define OFF_Q (4096*768)                 // 3,145,728
#define OFF_K (OFF_Q + 2*16*2048*16)     // +1,048,576
#define OFF_V (OFF_K + 2*16*2064*16)     // +1,056,768
// total = OFF_V + 1,056,768 = 6,307,840 floats = 25.2 MB

// ---------------------------------------------------------------------------
// Kernel 1: fused QKV projection.  P[row, c] for row=(b*2048+s), c in [0,768):
//   c<256   -> Q head h=c>>4, e=c&15
//   c<512   -> K
//   c>=512  -> V channel c-512
// Simple 64x64-tile fp32 GEMM, 256 threads, 4x4 acc per thread.
// ---------------------------------------------------------------------------
__global__ __launch_bounds__(256) void qkv_gemm(
    const float* __restrict__ A,   // resid (4096,768)
    const float* __restrict__ WQ, const float* __restrict__ WK,
    const float* __restrict__ WV,
    const float* __restrict__ bQ, const float* __restrict__ bK,
    const float* __restrict__ bV,
    float* __restrict__ P)
{
    __shared__ float As[16][65];   // +1 pad: avoids 16-way store conflict
    __shared__ float Bs[16][68];
    const int tid = threadIdx.x;
    const int m0 = blockIdx.y * 64;
    const int n0 = blockIdx.x * 64;
    const int tx = tid & 15, ty = tid >> 4;

    float acc[4][4];
#pragma unroll
    for (int i = 0; i < 4; ++i)
#pragma unroll
        for (int j = 0; j < 4; ++j) acc[i][j] = 0.f;

    for (int k0 = 0; k0 < DM; k0 += 16) {
#pragma unroll
        for (int i = 0; i < 4; ++i) {
            int idx = tid + i * 256;
            int m = idx >> 4, k = idx & 15;
            As[k][m] = A[(size_t)(m0 + m) * DM + k0 + k];
        }
#pragma unroll
        for (int i = 0; i < 4; ++i) {
            int idx = tid + i * 256;
            int k = idx >> 6, n = idx & 63;
            int c = n0 + n;
            int d = k0 + k;
            float w;
            if (c < 256)      w = WQ[((size_t)(c >> 4) * DM + d) * 16 + (c & 15)];
            else if (c < 512) w = WK[((size_t)((c - 256) >> 4) * DM + d) * 16 + (c & 15)];
            else              w = WV[(size_t)(c - 512) * DM + d];
            Bs[k][n] = w;
        }
        __syncthreads();
#pragma unroll
        for (int k = 0; k < 16; ++k) {
            float a[4], b[4];
#pragma unroll
            for (int i = 0; i < 4; ++i) a[i] = As[k][ty * 4 + i];
#pragma unroll
            for (int j = 0; j < 4; ++j) b[j] = Bs[k][tx * 4 + j];
#pragma unroll
            for (int i = 0; i < 4; ++i)
#pragma unroll
                for (int j = 0; j < 4; ++j) acc[i][j] = fmaf(a[i], b[j], acc[i][j]);
        }
        __syncthreads();
    }
#pragma unroll
    for (int j = 0; j < 4; ++j) {
        int c = n0 + tx * 4 + j;
        float bias = (c < 256) ? bQ[c] : (c < 512 ? bK[c - 256] : bV[c - 512]);
#pragma unroll
        for (int i = 0; i < 4; ++i)
            P[(size_t)(m0 + ty * 4 + i) * DM + c] = acc[i][j] + bias;
    }
}

// ---------------------------------------------------------------------------
// Kernel 2: rotary + scatter into attention layouts + append virtual k/v.
//  Q: (b,h,s,e)  s<2048 ;  K,V: (b,h,j,e/r)  j<2064.
//  One thread per (b,h,s[0..2063]).
//  freq[e] = 10000^(e/8) = 10^(e/2) (exact table, fp32 division as reference).
// ---------------------------------------------------------------------------
__global__ __launch_bounds__(256) void rope_scatter(
    const float* __restrict__ P,
    const float* __restrict__ vK, const float* __restrict__ vV,
    float* __restrict__ Q, float* __restrict__ K, float* __restrict__ V)
{
    const int t = blockIdx.x * 256 + threadIdx.x;
    const int total = B_ * H_ * SK;
    if (t >= total) return;
    const int s = t % SK;
    const int h = (t / SK) % H_;
    const int b = t / (SK * H_);

    float* Kd = K + (size_t)((b * H_ + h) * SK + s) * 16;
    float* Vd = V + (size_t)((b * H_ + h) * SK + s) * 16;

    if (s < S_) {
        const float* pr = P + (size_t)(b * S_ + s) * DM;
        float qv[16], kv[16], vv[16];
#pragma unroll
        for (int e = 0; e < 16; e += 4) {
            *(float4*)&qv[e] = *(const float4*)(pr + h * 16 + e);
            *(float4*)&kv[e] = *(const float4*)(pr + 256 + h * 16 + e);
            *(float4*)&vv[e] = *(const float4*)(pr + 512 + h * 16 + e);
        }
        const float freqs[8] = {1.0f, 3.1622776601683795f, 10.0f, 31.622776601683793f,
                                100.0f, 316.22776601683796f, 1000.0f, 3162.2776601683795f};
        float qo[16], ko[16];
#pragma unroll
        for (int e = 0; e < 8; ++e) {
            float ang = (float)s / freqs[e];
            float sn = sinf(ang), cs = cosf(ang);
            // rot[e] = -x[e+8] (e<8);  rot[e+8] = x[e]
            qo[e]     = qv[e]     * cs - qv[e + 8] * sn;
            qo[e + 8] = qv[e + 8] * cs + qv[e]     * sn;
            ko[e]     = kv[e]     * cs - kv[e + 8] * sn;
            ko[e + 8] = kv[e + 8] * cs + kv[e]     * sn;
        }
        float* Qd = Q + (size_t)((b * H_ + h) * S_ + s) * 16;
#pragma unroll
        for (int e = 0; e < 16; e += 4) {
            *(float4*)(Qd + e) = *(float4*)&qo[e];
            *(float4*)(Kd + e) = *(float4*)&ko[e];
            *(float4*)(Vd + e) = *(float4*)&vv[e];
        }
    } else {
        const int tt = s - S_;  // virtual slot, NOT rotated, no bias
#pragma unroll
        for (int e = 0; e < 16; e += 4) {
            *(float4*)(Kd + e) = *(const float4*)(vK + (size_t)tt * 256 + h * 16 + e);
            *(float4*)(Vd + e) = *(const float4*)(vV + (size_t)tt * 256 + h * 16 + e);
        }
    }
}

// ---------------------------------------------------------------------------
// Kernel 3: band-masked flash attention. 1 wave per block, thread = 1 query.
// Mask is exactly: key j visible iff j <= q+16 (covers band, tail, virtual).
// Fully-unrolled 64-key tile keeps sc[] in registers (no scratch).
// ---------------------------------------------------------------------------
__global__ __launch_bounds__(64) void attn_kernel(
    const float* __restrict__ Q, const float* __restrict__ K,
    const float* __restrict__ V, float* __restrict__ Z)
{
    const int bh   = blockIdx.y;           // 0..31 = b*16+h
    const int q0   = blockIdx.x * 64;
    const int lane = threadIdx.x;
    const int q    = q0 + lane;

    float qreg[16];
    const float* Qp = Q + (size_t)(bh * S_ + q) * 16;
#pragma unroll
    for (int e = 0; e < 16; e += 4) {
        float4 v4 = *(const float4*)(Qp + e);
        qreg[e] = v4.x * 0.25f; qreg[e + 1] = v4.y * 0.25f;   // fold 1/SCALE
        qreg[e + 2] = v4.z * 0.25f; qreg[e + 3] = v4.w * 0.25f;
    }
    float m = -INFINITY, l = 0.f;
    float acc[16];
#pragma unroll
    for (int r = 0; r < 16; ++r) acc[r] = 0.f;

    __shared__ float Ks[64][20];   // +4 pad: conflict-free b128 staging
    __shared__ float Vs[64][20];
    const float* Kbase = K + (size_t)bh * SK * 16;
    const float* Vbase = V + (size_t)bh * SK * 16;
    const int qp16 = q + 16;
    const int jmax = min(q0 + 64 - 1 + VKV_, SK - 1);

    for (int j0 = 0; j0 <= jmax; j0 += 64) {
        const int j = j0 + lane;
        if (j <= jmax) {
#pragma unroll
            for (int e = 0; e < 16; e += 4) {
                *(float4*)&Ks[lane][e] = *(const float4*)(Kbase + (size_t)j * 16 + e);
                *(float4*)&Vs[lane][e] = *(const float4*)(Vbase + (size_t)j * 16 + e);
            }
        }
        __syncthreads();

        float sc[64];
        float tmax = -INFINITY;
#pragma unroll
        for (int jj = 0; jj < 64; ++jj) {
            float s = 0.f;
#pragma unroll
            for (int e = 0; e < 16; ++e) s = fmaf(qreg[e], Ks[jj][e], s);
            s = (j0 + jj <= qp16) ? s : -INFINITY;
            sc[jj] = s;
            tmax = fmaxf(tmax, s);
        }
        const float mnew = fmaxf(m, tmax);
        const float scale = __expf(m - mnew);   // m=-inf first tile -> 0
        l *= scale;
#pragma unroll
        for (int r = 0; r < 16; ++r) acc[r] *= scale;
#pragma unroll
        for (int jj = 0; jj < 64; ++jj) {
            const float p = __expf(sc[jj] - mnew);  // masked -> exp(-inf)=0
            l += p;
#pragma unroll
            for (int r = 0; r < 16; ++r) acc[r] = fmaf(p, Vs[jj][r], acc[r]);
        }
        m = mnew;
        __syncthreads();
    }
    const float inv = 1.f / l;
    const int b = bh >> 4, h = bh & 15;
    float* zp = Z + (size_t)(b * S_ + q) * C_ + h * 16;
#pragma unroll
    for (int r = 0; r < 16; r += 4) {
        float4 o;
        o.x = acc[r] * inv; o.y = acc[r + 1] * inv;
        o.z = acc[r + 2] * inv; o.w = acc[r + 3] * inv;
        *(float4*)(zp + r) = o;
    }
}

// ---------------------------------------------------------------------------
// Kernel 4: output projection. out[row,m] = sum_h Z[row,h]*WO[h*768+m] + bO[m]
// ---------------------------------------------------------------------------
__global__ __launch_bounds__(256) void out_gemm(
    const float* __restrict__ Zm, const float* __restrict__ WO,
    const float* __restrict__ bO, float* __restrict__ out)
{
    __shared__ float As[16][65];
    __shared__ float Bs[16][68];
    const int tid = threadIdx.x;
    const int m0 = blockIdx.y * 64;
    const int n0 = blockIdx.x * 64;
    const int tx = tid & 15, ty = tid >> 4;

    float acc[4][4];
#pragma unroll
    for (int i = 0; i < 4; ++i)
#pragma unroll
        for (int j = 0; j < 4; ++j) acc[i][j] = 0.f;

    for (int k0 = 0; k0 < 256; k0 += 16) {
#pragma unroll
        for (int i = 0; i < 4; ++i) {
            int idx = tid + i * 256;
            int m = idx >> 4, k = idx & 15;
            As[k][m] = Zm[(size_t)(m0 + m) * 256 + k0 + k];
        }
#pragma unroll
        for (int i = 0; i < 4; ++i) {
            int idx = tid + i * 256;
            int k = idx >> 6, n = idx & 63;
            Bs[k][n] = WO[(size_t)(k0 + k) * DM + n0 + n];
        }
        __syncthreads();
#pragma unroll
        for (int k = 0; k < 16; ++k) {
            float a[4], b[4];
#pragma unroll
            for (int i = 0; i < 4; ++i) a[i] = As[k][ty * 4 + i];
#pragma unroll
            for (int j = 0; j < 4; ++j) b[j] = Bs[k][tx * 4 + j];
#pragma unroll
            for (int i = 0; i < 4; ++i)
#pragma unroll
                for (int j = 0; j < 4; ++j) acc[i][j] = fmaf(a[i], b[j], acc[i][j]);
        }
        __syncthreads();
    }
#pragma unroll
    for (int j = 0; j < 4; ++j) {
        int c = n0 + tx * 4 + j;
        float bias = bO[c];
#pragma unroll
        for (int i = 0; i < 4; ++i)
            out[(size_t)(m0 + ty * 4 + i) * DM + c] = acc[i][j] + bias;
    }
}

extern "C" void kernel_launch(void* const* d_in, const int* in_sizes, int n_in,
                              void* d_out, int out_size, void* d_ws, size_t ws_size,
                              hipStream_t stream)
{
    const float* resid = (const float*)d_in[0];
    const float* WQ = (const float*)d_in[1];
    const float* WK = (const float*)d_in[2];
    const float* WV = (const float*)d_in[3];
    const float* WO = (const float*)d_in[4];
    const float* bQ = (const float*)d_in[5];
    const float* bK = (const float*)d_in[6];
    const float* bV = (const float*)d_in[7];
    const float* bO = (const float*)d_in[8];
    const float* vK = (const float*)d_in[9];
    const float* vV = (const float*)d_in[10];
    float* out = (float*)d_out;
    float* ws  = (float*)d_ws;

    float* P  = ws + OFF_P;
    float* Qb = ws + OFF_Q;
    float* Kb = ws + OFF_K;
    float* Vb = ws + OFF_V;
    float* Zb = ws + OFF_Z;   // aliases P (P dead after rope_scatter)

    qkv_gemm<<<dim3(12, 64), 256, 0, stream>>>(resid, WQ, WK, WV, bQ, bK, bV, P);
    rope_scatter<<<dim3((B_ * H_ * SK + 255) / 256), 256, 0, stream>>>(P, vK, vV, Qb, Kb, Vb);
    attn_kernel<<<dim3(S_ / 64, B_ * H_), 64, 0, stream>>>(Qb, Kb, Vb, Zb);
    out_gemm<<<dim3(12, 64), 256, 0, stream>>>(Zb, WO, bO, out);
}

// Round 2
// 207.313 us; speedup vs baseline: 2.1223x; 2.1223x over previous
//
#include <hip/hip_runtime.h>
#include <hip/hip_bf16.h>
#include <math.h>

// Problem constants
#define B_   2
#define S_   2048
#define DM   768
#define H_   16      // N_QK
#define C_   256     // N_OV
#define VKV_ 16
#define SK   2064    // S_ + VKV_
#define SKP  2080    // padded to multiple of 32 (tail tile reads; rows >=2064 zeroed)

typedef __attribute__((ext_vector_type(8))) short short8;   // 8 bf16 (4 VGPRs)
typedef __attribute__((ext_vector_type(4))) float f32x4;

// log2(e) / SCALE, folded into Q at bf16-conversion time so p = exp2(t - tmax)
#define QSCALE 0.360673760222240851f

// Workspace layout. Z aliases P (P is dead after rope_scatter2).
#define OFF_P 0
#define OFF_Z 0
#define FP32_END (4096*768)              // 3,145,728 floats
// bf16 region (shorts), starting at ws + FP32_END floats:
#define NQB (32*2048*16)                 // 1,048,576 shorts
#define NKB (32*SKP*16)                  // 1,064,960 shorts
// Vt after Kb: 32*16*SKP shorts

__device__ __forceinline__ short tobf(float f) {
    union { float f; unsigned u; } x; x.f = f;
    unsigned r = x.u + 0x7FFFu + ((x.u >> 16) & 1u);   // RNE
    return (short)(r >> 16);
}

// ---------------------------------------------------------------------------
// Kernel 1: fused QKV projection (fp32).  P[row, c], row=b*2048+s, c in [0,768)
// ---------------------------------------------------------------------------
__global__ __launch_bounds__(256) void qkv_gemm(
    const float* __restrict__ A,
    const float* __restrict__ WQ, const float* __restrict__ WK,
    const float* __restrict__ WV,
    const float* __restrict__ bQ, const float* __restrict__ bK,
    const float* __restrict__ bV,
    float* __restrict__ P)
{
    __shared__ float As[16][65];
    __shared__ float Bs[16][68];
    const int tid = threadIdx.x;
    const int m0 = blockIdx.y * 64;
    const int n0 = blockIdx.x * 64;
    const int tx = tid & 15, ty = tid >> 4;

    float acc[4][4];
#pragma unroll
    for (int i = 0; i < 4; ++i)
#pragma unroll
        for (int j = 0; j < 4; ++j) acc[i][j] = 0.f;

    for (int k0 = 0; k0 < DM; k0 += 16) {
#pragma unroll
        for (int i = 0; i < 4; ++i) {
            int idx = tid + i * 256;
            int m = idx >> 4, k = idx & 15;
            As[k][m] = A[(size_t)(m0 + m) * DM + k0 + k];
        }
#pragma unroll
        for (int i = 0; i < 4; ++i) {
            int idx = tid + i * 256;
            int k = idx >> 6, n = idx & 63;
            int c = n0 + n;
            int d = k0 + k;
            float w;
            if (c < 256)      w = WQ[((size_t)(c >> 4) * DM + d) * 16 + (c & 15)];
            else if (c < 512) w = WK[((size_t)((c - 256) >> 4) * DM + d) * 16 + (c & 15)];
            else              w = WV[(size_t)(c - 512) * DM + d];
            Bs[k][n] = w;
        }
        __syncthreads();
#pragma unroll
        for (int k = 0; k < 16; ++k) {
            float a[4], b[4];
#pragma unroll
            for (int i = 0; i < 4; ++i) a[i] = As[k][ty * 4 + i];
#pragma unroll
            for (int j = 0; j < 4; ++j) b[j] = Bs[k][tx * 4 + j];
#pragma unroll
            for (int i = 0; i < 4; ++i)
#pragma unroll
                for (int j = 0; j < 4; ++j) acc[i][j] = fmaf(a[i], b[j], acc[i][j]);
        }
        __syncthreads();
    }
#pragma unroll
    for (int j = 0; j < 4; ++j) {
        int c = n0 + tx * 4 + j;
        float bias = (c < 256) ? bQ[c] : (c < 512 ? bK[c - 256] : bV[c - 512]);
#pragma unroll
        for (int i = 0; i < 4; ++i)
            P[(size_t)(m0 + ty * 4 + i) * DM + c] = acc[i][j] + bias;
    }
}

// ---------------------------------------------------------------------------
// Kernel 2: rotary + bf16 conversion + scatter.
//  Qb bf16 [bh][s<2048][16]  (pre-scaled by log2e/4)
//  Kb bf16 [bh][j<2080][16]  (rows >= 2064 zero)
//  Vt bf16 [bh][dv<16][j<2080]  (cols >= 2064 zero)
// ---------------------------------------------------------------------------
__global__ __launch_bounds__(256) void rope_scatter2(
    const float* __restrict__ P,
    const float* __restrict__ vK, const float* __restrict__ vV,
    short* __restrict__ Qb, short* __restrict__ Kb, short* __restrict__ Vt)
{
    const int t = blockIdx.x * 256 + threadIdx.x;
    if (t >= 32 * SKP) return;
    const int s  = t % SKP;
    const int bh = t / SKP;
    const int h  = bh & 15;
    const int b  = bh >> 4;

    short kb[16], vb[16];

    if (s < S_) {
        const float* pr = P + (size_t)(b * S_ + s) * DM;
        float qv[16], kv[16], vv[16];
#pragma unroll
        for (int e = 0; e < 16; e += 4) {
            *(float4*)&qv[e] = *(const float4*)(pr + h * 16 + e);
            *(float4*)&kv[e] = *(const float4*)(pr + 256 + h * 16 + e);
            *(float4*)&vv[e] = *(const float4*)(pr + 512 + h * 16 + e);
        }
        const float freqs[8] = {1.0f, 3.1622776601683795f, 10.0f, 31.622776601683793f,
                                100.0f, 316.22776601683796f, 1000.0f, 3162.2776601683795f};
        short qb[16];
#pragma unroll
        for (int e = 0; e < 8; ++e) {
            float ang = (float)s / freqs[e];
            float sn = sinf(ang), cs = cosf(ang);
            float q0 = qv[e] * cs - qv[e + 8] * sn;
            float q1 = qv[e + 8] * cs + qv[e] * sn;
            float k0 = kv[e] * cs - kv[e + 8] * sn;
            float k1 = kv[e + 8] * cs + kv[e] * sn;
            qb[e] = tobf(q0 * QSCALE); qb[e + 8] = tobf(q1 * QSCALE);
            kb[e] = tobf(k0);          kb[e + 8] = tobf(k1);
            vb[e] = tobf(vv[e]);       vb[e + 8] = tobf(vv[e + 8]);
        }
        union { short s[16]; short8 v[2]; } qu;
#pragma unroll
        for (int e = 0; e < 16; ++e) qu.s[e] = qb[e];
        short8* qd = (short8*)(Qb + ((size_t)bh * S_ + s) * 16);
        qd[0] = qu.v[0]; qd[1] = qu.v[1];
    } else if (s < SK) {
        const int tt = s - S_;
#pragma unroll
        for (int e = 0; e < 16; ++e) {
            kb[e] = tobf(vK[(size_t)tt * 256 + h * 16 + e]);
            vb[e] = tobf(vV[(size_t)tt * 256 + h * 16 + e]);
        }
    } else {
#pragma unroll
        for (int e = 0; e < 16; ++e) { kb[e] = 0; vb[e] = 0; }
    }

    union { short s[16]; short8 v[2]; } ku;
#pragma unroll
    for (int e = 0; e < 16; ++e) ku.s[e] = kb[e];
    short8* kd = (short8*)(Kb + ((size_t)bh * SKP + s) * 16);
    kd[0] = ku.v[0]; kd[1] = ku.v[1];
#pragma unroll
    for (int dv = 0; dv < 16; ++dv)
        Vt[((size_t)bh * 16 + dv) * SKP + s] = vb[dv];
}

// ---------------------------------------------------------------------------
// Kernel 3: MFMA flash attention, swapped-QK orientation.
//  Block = 4 independent waves; wave w handles 16 queries q0w..q0w+15 of (bh).
//  Per 32-key tile: S_sw = K·Q^T (2 mfma, e padded 16->32), online softmax
//  (2 shfl_xor row-reduce), P relayout (4 cvt_pk + 8 bpermute), O_sw = V^T·P_sw.
// ---------------------------------------------------------------------------
__global__ __launch_bounds__(256) void attn_mfma(
    const short* __restrict__ Qb, const short* __restrict__ Kb,
    const short* __restrict__ Vt, float* __restrict__ Z)
{
    const int bh   = blockIdx.y;
    const int w    = threadIdx.x >> 6;
    const int lane = threadIdx.x & 63;
    const int g    = lane >> 4;
    const int c    = lane & 15;
    const int q0w  = blockIdx.x * 64 + w * 16;

    const short8 zero8 = {0,0,0,0,0,0,0,0};
    const f32x4  zero4 = {0.f,0.f,0.f,0.f};

    // Q fragment (B operand of swapped QK): lane needs Q[q0w+c][8*(g&1)+i], 0 for g>=2
    short8 qf = *(const short8*)(Qb + ((size_t)(bh * S_ + q0w + c)) * 16 + 8 * (g & 1));
    if (g >= 2) qf = zero8;

    f32x4 acc = zero4;           // O_sw[dv=4g+r][q=c]
    float m = -INFINITY;
    float lsum = 0.f;
    const int qv16 = q0w + c + 16;    // visibility bound for this lane's query
    const int jmax = q0w + 31;        // last key any query of this wave can see

    const size_t kbase = (size_t)bh * SKP * 16;
    const size_t vbase = (size_t)bh * 16 * SKP;
    const int srcA = ((g & 1) << 5) + c;   // P-relayout source lanes
    const int srcB = srcA + 16;

    for (int kt = 0; kt <= jmax; kt += 32) {
        short8 ka0 = *(const short8*)(Kb + kbase + (size_t)(kt + c) * 16 + 8 * (g & 1));
        short8 ka1 = *(const short8*)(Kb + kbase + (size_t)(kt + 16 + c) * 16 + 8 * (g & 1));
        if (g >= 2) { ka0 = zero8; ka1 = zero8; }
        short8 vf = *(const short8*)(Vt + vbase + (size_t)c * SKP + kt + 8 * g);

        // S_sw tiles: lane holds s0[r]=t[key kt+4g+r][q=c], s1[r]=t[key kt+16+4g+r][q=c]
        f32x4 s0 = __builtin_amdgcn_mfma_f32_16x16x32_bf16(ka0, qf, zero4, 0, 0, 0);
        f32x4 s1 = __builtin_amdgcn_mfma_f32_16x16x32_bf16(ka1, qf, zero4, 0, 0, 0);

        if (kt + 31 > q0w + 16) {     // tile not fully visible for all queries
#pragma unroll
            for (int r = 0; r < 4; ++r) {
                s0[r] = (kt + 4 * g + r <= qv16) ? s0[r] : -INFINITY;
                s1[r] = (kt + 16 + 4 * g + r <= qv16) ? s1[r] : -INFINITY;
            }
        }
        float tm = fmaxf(fmaxf(fmaxf(s0[0], s0[1]), fmaxf(s0[2], s0[3])),
                         fmaxf(fmaxf(s1[0], s1[1]), fmaxf(s1[2], s1[3])));
        tm = fmaxf(tm, __shfl_xor(tm, 16));
        tm = fmaxf(tm, __shfl_xor(tm, 32));
        const float mnew = fmaxf(m, tm);
        const float f = __builtin_amdgcn_exp2f(m - mnew);   // first tile: exp2(-inf)=0

        const float p00 = __builtin_amdgcn_exp2f(s0[0] - mnew);
        const float p01 = __builtin_amdgcn_exp2f(s0[1] - mnew);
        const float p02 = __builtin_amdgcn_exp2f(s0[2] - mnew);
        const float p03 = __builtin_amdgcn_exp2f(s0[3] - mnew);
        const float p10 = __builtin_amdgcn_exp2f(s1[0] - mnew);
        const float p11 = __builtin_amdgcn_exp2f(s1[1] - mnew);
        const float p12 = __builtin_amdgcn_exp2f(s1[2] - mnew);
        const float p13 = __builtin_amdgcn_exp2f(s1[3] - mnew);

        lsum = lsum * f + ((p00 + p01) + (p02 + p03)) + ((p10 + p11) + (p12 + p13));
        acc[0] *= f; acc[1] *= f; acc[2] *= f; acc[3] *= f;

        // pack P to bf16 pairs
        unsigned P01, P23, Q01, Q23;
        asm("v_cvt_pk_bf16_f32 %0, %1, %2" : "=v"(P01) : "v"(p00), "v"(p01));
        asm("v_cvt_pk_bf16_f32 %0, %1, %2" : "=v"(P23) : "v"(p02), "v"(p03));
        asm("v_cvt_pk_bf16_f32 %0, %1, %2" : "=v"(Q01) : "v"(p10), "v"(p11));
        asm("v_cvt_pk_bf16_f32 %0, %1, %2" : "=v"(Q23) : "v"(p12), "v"(p13));

        // relayout D->B operand: lane (g,c) VGPR j holds keys kt+8g+2j, +1
        unsigned t0 = (unsigned)__shfl((int)P01, srcA);
        unsigned u0 = (unsigned)__shfl((int)Q01, srcA);
        unsigned t1 = (unsigned)__shfl((int)P23, srcA);
        unsigned u1 = (unsigned)__shfl((int)Q23, srcA);
        unsigned t2 = (unsigned)__shfl((int)P01, srcB);
        unsigned u2 = (unsigned)__shfl((int)Q01, srcB);
        unsigned t3 = (unsigned)__shfl((int)P23, srcB);
        unsigned u3 = (unsigned)__shfl((int)Q23, srcB);
        union { unsigned u[4]; short8 v; } bp;
        bp.u[0] = (g < 2) ? t0 : u0;
        bp.u[1] = (g < 2) ? t1 : u1;
        bp.u[2] = (g < 2) ? t2 : u2;
        bp.u[3] = (g < 2) ? t3 : u3;

        // O_sw += V^T · P_sw
        acc = __builtin_amdgcn_mfma_f32_16x16x32_bf16(vf, bp.v, acc, 0, 0, 0);
        m = mnew;
    }

    // combine the 4 lane-replica partial sums of l for query c
    lsum += __shfl_xor(lsum, 16);
    lsum += __shfl_xor(lsum, 32);
    const float inv = 1.f / lsum;

    const int b = bh >> 4, h = bh & 15;
    float* zp = Z + ((size_t)(b * S_ + q0w + c)) * C_ + h * 16 + 4 * g;
    f32x4 o = acc * inv;
    *(f32x4*)zp = o;
}

// ---------------------------------------------------------------------------
// Kernel 4: output projection (fp32)
// ---------------------------------------------------------------------------
__global__ __launch_bounds__(256) void out_gemm(
    const float* __restrict__ Zm, const float* __restrict__ WO,
    const float* __restrict__ bO, float* __restrict__ out)
{
    __shared__ float As[16][65];
    __shared__ float Bs[16][68];
    const int tid = threadIdx.x;
    const int m0 = blockIdx.y * 64;
    const int n0 = blockIdx.x * 64;
    const int tx = tid & 15, ty = tid >> 4;

    float acc[4][4];
#pragma unroll
    for (int i = 0; i < 4; ++i)
#pragma unroll
        for (int j = 0; j < 4; ++j) acc[i][j] = 0.f;

    for (int k0 = 0; k0 < 256; k0 += 16) {
#pragma unroll
        for (int i = 0; i < 4; ++i) {
            int idx = tid + i * 256;
            int m = idx >> 4, k = idx & 15;
            As[k][m] = Zm[(size_t)(m0 + m) * 256 + k0 + k];
        }
#pragma unroll
        for (int i = 0; i < 4; ++i) {
            int idx = tid + i * 256;
            int k = idx >> 6, n = idx & 63;
            Bs[k][n] = WO[(size_t)(k0 + k) * DM + n0 + n];
        }
        __syncthreads();
#pragma unroll
        for (int k = 0; k < 16; ++k) {
            float a[4], b[4];
#pragma unroll
            for (int i = 0; i < 4; ++i) a[i] = As[k][ty * 4 + i];
#pragma unroll
            for (int j = 0; j < 4; ++j) b[j] = Bs[k][tx * 4 + j];
#pragma unroll
            for (int i = 0; i < 4; ++i)
#pragma unroll
                for (int j = 0; j < 4; ++j) acc[i][j] = fmaf(a[i], b[j], acc[i][j]);
        }
        __syncthreads();
    }
#pragma unroll
    for (int j = 0; j < 4; ++j) {
        int cc = n0 + tx * 4 + j;
        float bias = bO[cc];
#pragma unroll
        for (int i = 0; i < 4; ++i)
            out[(size_t)(m0 + ty * 4 + i) * DM + cc] = acc[i][j] + bias;
    }
}

extern "C" void kernel_launch(void* const* d_in, const int* in_sizes, int n_in,
                              void* d_out, int out_size, void* d_ws, size_t ws_size,
                              hipStream_t stream)
{
    const float* resid = (const float*)d_in[0];
    const float* WQ = (const float*)d_in[1];
    const float* WK = (const float*)d_in[2];
    const float* WV = (const float*)d_in[3];
    const float* WO = (const float*)d_in[4];
    const float* bQ = (const float*)d_in[5];
    const float* bK = (const float*)d_in[6];
    const float* bV = (const float*)d_in[7];
    const float* bO = (const float*)d_in[8];
    const float* vK = (const float*)d_in[9];
    const float* vV = (const float*)d_in[10];
    float* out = (float*)d_out;
    float* ws  = (float*)d_ws;

    float* P  = ws + OFF_P;
    float* Zb = ws + OFF_Z;                   // aliases P
    short* Qb = (short*)(ws + FP32_END);
    short* Kb = Qb + NQB;
    short* Vt = Kb + NKB;

    qkv_gemm<<<dim3(12, 64), 256, 0, stream>>>(resid, WQ, WK, WV, bQ, bK, bV, P);
    rope_scatter2<<<dim3((32 * SKP + 255) / 256), 256, 0, stream>>>(P, vK, vV, Qb, Kb, Vt);
    attn_mfma<<<dim3(32, 32), 256, 0, stream>>>(Qb, Kb, Vt, Zb);
    out_gemm<<<dim3(12, 64), 256, 0, stream>>>(Zb, WO, bO, out);
}

// Round 3
// 97.217 us; speedup vs baseline: 4.5258x; 2.1325x over previous
//
#include <hip/hip_runtime.h>
#include <hip/hip_bf16.h>
#include <math.h>

// Problem constants
#define B_   2
#define S_   2048
#define DM   768
#define H_   16      // N_QK
#define C_   256     // N_OV
#define VKV_ 16
#define SK   2064    // S_ + VKV_
#define SKP  2080    // padded to multiple of 32 (rows >=2064 zeroed)

typedef __attribute__((ext_vector_type(8))) short short8;   // 8 bf16
typedef __attribute__((ext_vector_type(4))) short short4v;
typedef __attribute__((ext_vector_type(4))) float f32x4;

// log2(e) / SCALE folded into Q so p = exp2(s - max)
#define QSCALE 0.360673760222240851f

__device__ __forceinline__ short tobf(float f) {
    union { float f; unsigned u; } x; x.f = f;
    unsigned r = x.u + 0x7FFFu + ((x.u >> 16) & 1u);   // RNE
    return (short)(r >> 16);
}

__device__ __forceinline__ void gload_lds16(const short* g, short* l) {
    __builtin_amdgcn_global_load_lds(
        (const __attribute__((address_space(1))) unsigned int*)g,
        (__attribute__((address_space(3))) unsigned int*)l, 16, 0, 0);
}

// ---------------------------------------------------------------------------
// conv_bf16: fp32 -> bf16, 4 elements/thread
// ---------------------------------------------------------------------------
__global__ __launch_bounds__(256) void conv_bf16(
    const float* __restrict__ in, short* __restrict__ out, int n)
{
    int t = (blockIdx.x * 256 + threadIdx.x) * 4;
    if (t >= n) return;
    float4 v = *(const float4*)(in + t);
    short4v o = { tobf(v.x), tobf(v.y), tobf(v.z), tobf(v.w) };
    *(short4v*)(out + t) = o;
}

// ---------------------------------------------------------------------------
// conv_weights: pack Wqkv_t [768 c][768 d] bf16, bqkv[768] f32, WtO [768 m][256 c]
// ---------------------------------------------------------------------------
__global__ __launch_bounds__(256) void conv_weights(
    const float* __restrict__ WQ, const float* __restrict__ WK,
    const float* __restrict__ WV, const float* __restrict__ WO,
    const float* __restrict__ bQ, const float* __restrict__ bK,
    const float* __restrict__ bV,
    short* __restrict__ Wqkv_t, float* __restrict__ bqkv, short* __restrict__ WtO)
{
    int t = blockIdx.x * 256 + threadIdx.x;
    if (t < 768 * 768) {
        int cc = t / 768, d = t % 768;
        float w;
        if (cc < 256)      w = WQ[((size_t)(cc >> 4) * DM + d) * 16 + (cc & 15)];
        else if (cc < 512) w = WK[((size_t)((cc - 256) >> 4) * DM + d) * 16 + (cc & 15)];
        else               w = WV[(size_t)(cc - 512) * DM + d];
        Wqkv_t[t] = tobf(w);
    } else if (t < 768 * 768 + 768 * 256) {
        int u = t - 768 * 768;
        int c = u & 255, m = u >> 8;
        WtO[u] = tobf(WO[(size_t)c * DM + m]);
    } else if (t < 768 * 768 + 768 * 256 + 768) {
        int c = t - (768 * 768 + 768 * 256);
        bqkv[c] = (c < 256) ? bQ[c] : (c < 512 ? bK[c - 256] : bV[c - 512]);
    }
}

// ---------------------------------------------------------------------------
// mm_mfma<KDIM>: C[M=4096][768] = A[4096][KDIM] * Bt[768][KDIM]^T + bias
//  bf16 MFMA, tile 128x64, 4 waves (2Mx2N), BK=64.
//  LDS staged via global_load_lds(16B), T2 XOR-swizzle via pre-swizzled source.
// ---------------------------------------------------------------------------
template<int KDIM>
__global__ __launch_bounds__(256) void mm_mfma(
    const short* __restrict__ A, const short* __restrict__ Bt,
    const float* __restrict__ bias, float* __restrict__ Cout)
{
    __shared__ short As[128 * 64];   // [row][64k], row stride 128 B, swizzled
    __shared__ short Bs[64 * 64];

    const int tid  = threadIdx.x;
    const int w    = tid >> 6;
    const int lane = tid & 63;
    const int wm   = w >> 1, wn = w & 1;
    const int g    = lane >> 4, c = lane & 15;
    const int m0   = blockIdx.y * 128;
    const int n0   = blockIdx.x * 64;

    f32x4 acc[4][2];
#pragma unroll
    for (int i = 0; i < 4; ++i)
#pragma unroll
        for (int j = 0; j < 2; ++j) acc[i][j] = (f32x4){0.f, 0.f, 0.f, 0.f};

    const int lr = lane >> 3;        // 0..7  sub-row within chunk
    const int lc = lane & 7;         // 0..7  16B-chunk col

    for (int k0 = 0; k0 < KDIM; k0 += 64) {
        // stage A: 16 chunks of 1KB (8 rows each); wave w takes chunks i*4+w
#pragma unroll
        for (int i = 0; i < 4; ++i) {
            const int ch  = i * 4 + w;
            const int row = ch * 8 + lr;
            const int scc = lc ^ (row & 7);
            gload_lds16(A + (size_t)(m0 + row) * KDIM + k0 + scc * 8,
                        As + ch * 512);
        }
        // stage B: 8 chunks
#pragma unroll
        for (int i = 0; i < 2; ++i) {
            const int ch  = i * 4 + w;
            const int row = ch * 8 + lr;
            const int scc = lc ^ (row & 7);
            gload_lds16(Bt + (size_t)(n0 + row) * KDIM + k0 + scc * 8,
                        Bs + ch * 512);
        }
        __syncthreads();
#pragma unroll
        for (int kk = 0; kk < 64; kk += 32) {
            short8 af[4], bf[2];
#pragma unroll
            for (int i = 0; i < 4; ++i) {
                const int row = wm * 64 + i * 16 + c;
                const int sc  = ((kk >> 3) + g) ^ (row & 7);
                af[i] = *(const short8*)(As + row * 64 + sc * 8);
            }
#pragma unroll
            for (int j = 0; j < 2; ++j) {
                const int row = wn * 32 + j * 16 + c;
                const int sc  = ((kk >> 3) + g) ^ (row & 7);
                bf[j] = *(const short8*)(Bs + row * 64 + sc * 8);
            }
#pragma unroll
            for (int i = 0; i < 4; ++i)
#pragma unroll
                for (int j = 0; j < 2; ++j)
                    acc[i][j] = __builtin_amdgcn_mfma_f32_16x16x32_bf16(
                        af[i], bf[j], acc[i][j], 0, 0, 0);
        }
        __syncthreads();
    }
    // epilogue: C[m0+wm*64+i*16+4g+r][n0+wn*32+j*16+c]
#pragma unroll
    for (int i = 0; i < 4; ++i)
#pragma unroll
        for (int j = 0; j < 2; ++j) {
            const int col = n0 + wn * 32 + j * 16 + c;
            const float bv = bias[col];
#pragma unroll
            for (int r = 0; r < 4; ++r) {
                const int row = m0 + wm * 64 + i * 16 + 4 * g + r;
                Cout[(size_t)row * DM + col] = acc[i][j][r] + bv;
            }
        }
}

// ---------------------------------------------------------------------------
// rope_scatter2: rotary + bf16 scatter.
//  Qb [bh][s<2048][16] (pre-scaled), Kb [bh][j<2080][16], Vt [bh][dv][j<2080]
// ---------------------------------------------------------------------------
__global__ __launch_bounds__(256) void rope_scatter2(
    const float* __restrict__ P,
    const float* __restrict__ vK, const float* __restrict__ vV,
    short* __restrict__ Qb, short* __restrict__ Kb, short* __restrict__ Vt)
{
    const int t = blockIdx.x * 256 + threadIdx.x;
    if (t >= 32 * SKP) return;
    const int s  = t % SKP;
    const int bh = t / SKP;
    const int h  = bh & 15;
    const int b  = bh >> 4;

    short kb[16], vb[16];

    if (s < S_) {
        const float* pr = P + (size_t)(b * S_ + s) * DM;
        float qv[16], kv[16], vv[16];
#pragma unroll
        for (int e = 0; e < 16; e += 4) {
            *(float4*)&qv[e] = *(const float4*)(pr + h * 16 + e);
            *(float4*)&kv[e] = *(const float4*)(pr + 256 + h * 16 + e);
            *(float4*)&vv[e] = *(const float4*)(pr + 512 + h * 16 + e);
        }
        const float freqs[8] = {1.0f, 3.1622776601683795f, 10.0f, 31.622776601683793f,
                                100.0f, 316.22776601683796f, 1000.0f, 3162.2776601683795f};
        short qb[16];
#pragma unroll
        for (int e = 0; e < 8; ++e) {
            float ang = (float)s / freqs[e];
            float sn = sinf(ang), cs = cosf(ang);
            float q0 = qv[e] * cs - qv[e + 8] * sn;
            float q1 = qv[e + 8] * cs + qv[e] * sn;
            float k0 = kv[e] * cs - kv[e + 8] * sn;
            float k1 = kv[e + 8] * cs + kv[e] * sn;
            qb[e] = tobf(q0 * QSCALE); qb[e + 8] = tobf(q1 * QSCALE);
            kb[e] = tobf(k0);          kb[e + 8] = tobf(k1);
            vb[e] = tobf(vv[e]);       vb[e + 8] = tobf(vv[e + 8]);
        }
        union { short s[16]; short8 v[2]; } qu;
#pragma unroll
        for (int e = 0; e < 16; ++e) qu.s[e] = qb[e];
        short8* qd = (short8*)(Qb + ((size_t)bh * S_ + s) * 16);
        qd[0] = qu.v[0]; qd[1] = qu.v[1];
    } else if (s < SK) {
        const int tt = s - S_;
#pragma unroll
        for (int e = 0; e < 16; ++e) {
            kb[e] = tobf(vK[(size_t)tt * 256 + h * 16 + e]);
            vb[e] = tobf(vV[(size_t)tt * 256 + h * 16 + e]);
        }
    } else {
#pragma unroll
        for (int e = 0; e < 16; ++e) { kb[e] = 0; vb[e] = 0; }
    }

    union { short s[16]; short8 v[2]; } ku;
#pragma unroll
    for (int e = 0; e < 16; ++e) ku.s[e] = kb[e];
    short8* kd = (short8*)(Kb + ((size_t)bh * SKP + s) * 16);
    kd[0] = ku.v[0]; kd[1] = ku.v[1];
#pragma unroll
    for (int dv = 0; dv < 16; ++dv)
        Vt[((size_t)bh * 16 + dv) * SKP + s] = vb[dv];
}

// ---------------------------------------------------------------------------
// attn_mfma: swapped-QK MFMA flash attention. bf16 Z output.
// ---------------------------------------------------------------------------
__global__ __launch_bounds__(256) void attn_mfma(
    const short* __restrict__ Qb, const short* __restrict__ Kb,
    const short* __restrict__ Vt, short* __restrict__ Zb)
{
    const int bh   = blockIdx.y;
    const int w    = threadIdx.x >> 6;
    const int lane = threadIdx.x & 63;
    const int g    = lane >> 4;
    const int c    = lane & 15;
    const int q0w  = blockIdx.x * 64 + w * 16;

    const short8 zero8 = {0,0,0,0,0,0,0,0};
    const f32x4  zero4 = {0.f,0.f,0.f,0.f};

    short8 qf = *(const short8*)(Qb + ((size_t)(bh * S_ + q0w + c)) * 16 + 8 * (g & 1));
    if (g >= 2) qf = zero8;

    f32x4 acc = zero4;
    float m = -INFINITY;
    float lsum = 0.f;
    const int qv16 = q0w + c + 16;
    const int jmax = q0w + 31;

    const size_t kbase = (size_t)bh * SKP * 16;
    const size_t vbase = (size_t)bh * 16 * SKP;
    const int srcA = ((g & 1) << 5) + c;
    const int srcB = srcA + 16;

    for (int kt = 0; kt <= jmax; kt += 32) {
        short8 ka0 = *(const short8*)(Kb + kbase + (size_t)(kt + c) * 16 + 8 * (g & 1));
        short8 ka1 = *(const short8*)(Kb + kbase + (size_t)(kt + 16 + c) * 16 + 8 * (g & 1));
        if (g >= 2) { ka0 = zero8; ka1 = zero8; }
        short8 vf = *(const short8*)(Vt + vbase + (size_t)c * SKP + kt + 8 * g);

        f32x4 s0 = __builtin_amdgcn_mfma_f32_16x16x32_bf16(ka0, qf, zero4, 0, 0, 0);
        f32x4 s1 = __builtin_amdgcn_mfma_f32_16x16x32_bf16(ka1, qf, zero4, 0, 0, 0);

        if (kt + 31 > q0w + 16) {
#pragma unroll
            for (int r = 0; r < 4; ++r) {
                s0[r] = (kt + 4 * g + r <= qv16) ? s0[r] : -INFINITY;
                s1[r] = (kt + 16 + 4 * g + r <= qv16) ? s1[r] : -INFINITY;
            }
        }
        float tm = fmaxf(fmaxf(fmaxf(s0[0], s0[1]), fmaxf(s0[2], s0[3])),
                         fmaxf(fmaxf(s1[0], s1[1]), fmaxf(s1[2], s1[3])));
        tm = fmaxf(tm, __shfl_xor(tm, 16));
        tm = fmaxf(tm, __shfl_xor(tm, 32));
        const float mnew = fmaxf(m, tm);
        const float f = __builtin_amdgcn_exp2f(m - mnew);

        const float p00 = __builtin_amdgcn_exp2f(s0[0] - mnew);
        const float p01 = __builtin_amdgcn_exp2f(s0[1] - mnew);
        const float p02 = __builtin_amdgcn_exp2f(s0[2] - mnew);
        const float p03 = __builtin_amdgcn_exp2f(s0[3] - mnew);
        const float p10 = __builtin_amdgcn_exp2f(s1[0] - mnew);
        const float p11 = __builtin_amdgcn_exp2f(s1[1] - mnew);
        const float p12 = __builtin_amdgcn_exp2f(s1[2] - mnew);
        const float p13 = __builtin_amdgcn_exp2f(s1[3] - mnew);

        lsum = lsum * f + ((p00 + p01) + (p02 + p03)) + ((p10 + p11) + (p12 + p13));
        acc[0] *= f; acc[1] *= f; acc[2] *= f; acc[3] *= f;

        unsigned P01, P23, Q01, Q23;
        asm("v_cvt_pk_bf16_f32 %0, %1, %2" : "=v"(P01) : "v"(p00), "v"(p01));
        asm("v_cvt_pk_bf16_f32 %0, %1, %2" : "=v"(P23) : "v"(p02), "v"(p03));
        asm("v_cvt_pk_bf16_f32 %0, %1, %2" : "=v"(Q01) : "v"(p10), "v"(p11));
        asm("v_cvt_pk_bf16_f32 %0, %1, %2" : "=v"(Q23) : "v"(p12), "v"(p13));

        unsigned t0 = (unsigned)__shfl((int)P01, srcA);
        unsigned u0 = (unsigned)__shfl((int)Q01, srcA);
        unsigned t1 = (unsigned)__shfl((int)P23, srcA);
        unsigned u1 = (unsigned)__shfl((int)Q23, srcA);
        unsigned t2 = (unsigned)__shfl((int)P01, srcB);
        unsigned u2 = (unsigned)__shfl((int)Q01, srcB);
        unsigned t3 = (unsigned)__shfl((int)P23, srcB);
        unsigned u3 = (unsigned)__shfl((int)Q23, srcB);
        union { unsigned u[4]; short8 v; } bp;
        bp.u[0] = (g < 2) ? t0 : u0;
        bp.u[1] = (g < 2) ? t1 : u1;
        bp.u[2] = (g < 2) ? t2 : u2;
        bp.u[3] = (g < 2) ? t3 : u3;

        acc = __builtin_amdgcn_mfma_f32_16x16x32_bf16(vf, bp.v, acc, 0, 0, 0);
        m = mnew;
    }

    lsum += __shfl_xor(lsum, 16);
    lsum += __shfl_xor(lsum, 32);
    const float inv = 1.f / lsum;

    const int b = bh >> 4, h = bh & 15;
    short* zp = Zb + ((size_t)(b * S_ + q0w + c)) * C_ + h * 16 + 4 * g;
    short4v zo = { tobf(acc[0] * inv), tobf(acc[1] * inv),
                   tobf(acc[2] * inv), tobf(acc[3] * inv) };
    *(short4v*)zp = zo;
}

extern "C" void kernel_launch(void* const* d_in, const int* in_sizes, int n_in,
                              void* d_out, int out_size, void* d_ws, size_t ws_size,
                              hipStream_t stream)
{
    const float* resid = (const float*)d_in[0];
    const float* WQ = (const float*)d_in[1];
    const float* WK = (const float*)d_in[2];
    const float* WV = (const float*)d_in[3];
    const float* WO = (const float*)d_in[4];
    const float* bQ = (const float*)d_in[5];
    const float* bK = (const float*)d_in[6];
    const float* bV = (const float*)d_in[7];
    const float* bO = (const float*)d_in[8];
    const float* vK = (const float*)d_in[9];
    const float* vV = (const float*)d_in[10];
    float* out = (float*)d_out;
    float* ws  = (float*)d_ws;

    float* P    = ws;                               // 3,145,728 f32
    float* bqkv = ws + 3145728;                     // 768 f32
    short* Ab   = (short*)(ws + 3145728 + 768);     // 3,145,728 bf16
    short* Wqt  = Ab + 3145728;                     // 589,824
    short* WtO  = Wqt + 589824;                     // 196,608
    short* Qb   = WtO + 196608;                     // 1,048,576
    short* Kb   = Qb + 1048576;                     // 1,064,960
    short* Vt   = Kb + 1064960;                     // 1,064,960
    short* Zb   = (short*)ws;                       // aliases P (dead after rope)

    conv_bf16<<<dim3(3072), 256, 0, stream>>>(resid, Ab, 4096 * 768);
    conv_weights<<<dim3(3075), 256, 0, stream>>>(WQ, WK, WV, WO, bQ, bK, bV,
                                                 Wqt, bqkv, WtO);
    mm_mfma<768><<<dim3(12, 32), 256, 0, stream>>>(Ab, Wqt, bqkv, P);
    rope_scatter2<<<dim3((32 * SKP + 255) / 256), 256, 0, stream>>>(P, vK, vV, Qb, Kb, Vt);
    attn_mfma<<<dim3(32, 32), 256, 0, stream>>>(Qb, Kb, Vt, Zb);
    mm_mfma<256><<<dim3(12, 32), 256, 0, stream>>>(Zb, WtO, bO, out);
}

// Round 4
// 96.186 us; speedup vs baseline: 4.5743x; 1.0107x over previous
//
#include <hip/hip_runtime.h>
#include <hip/hip_bf16.h>
#include <math.h>

// Problem constants
#define B_   2
#define S_   2048
#define DM   768
#define H_   16      // N_QK
#define C_   256     // N_OV
#define VKV_ 16
#define SK   2064    // S_ + VKV_
#define SKP  2080    // padded to multiple of 32 (rows >=2064 zeroed)

typedef __attribute__((ext_vector_type(8))) short short8;    // 8 bf16
typedef __attribute__((ext_vector_type(4))) short short4v;
typedef __attribute__((ext_vector_type(4))) float f32x4;
typedef __attribute__((ext_vector_type(16))) float f32x16;

// log2(e) / SCALE folded into Q so p = exp2(s - max)
#define QSCALE 0.360673760222240851f

__device__ __forceinline__ short tobf(float f) {
    union { float f; unsigned u; } x; x.f = f;
    unsigned r = x.u + 0x7FFFu + ((x.u >> 16) & 1u);   // RNE
    return (short)(r >> 16);
}

__device__ __forceinline__ void gload_lds16(const short* g, short* l) {
    __builtin_amdgcn_global_load_lds(
        (const __attribute__((address_space(1))) unsigned int*)g,
        (__attribute__((address_space(3))) unsigned int*)l, 16, 0, 0);
}

// ---------------------------------------------------------------------------
// conv_bf16: fp32 -> bf16, 4 elements/thread
// ---------------------------------------------------------------------------
__global__ __launch_bounds__(256) void conv_bf16(
    const float* __restrict__ in, short* __restrict__ out, int n)
{
    int t = (blockIdx.x * 256 + threadIdx.x) * 4;
    if (t >= n) return;
    float4 v = *(const float4*)(in + t);
    short4v o = { tobf(v.x), tobf(v.y), tobf(v.z), tobf(v.w) };
    *(short4v*)(out + t) = o;
}

// ---------------------------------------------------------------------------
// conv_weights: pack Wqkv_t [768 c][768 d] bf16, bqkv[768] f32, WtO [768 m][256 c]
// ---------------------------------------------------------------------------
__global__ __launch_bounds__(256) void conv_weights(
    const float* __restrict__ WQ, const float* __restrict__ WK,
    const float* __restrict__ WV, const float* __restrict__ WO,
    const float* __restrict__ bQ, const float* __restrict__ bK,
    const float* __restrict__ bV,
    short* __restrict__ Wqkv_t, float* __restrict__ bqkv, short* __restrict__ WtO)
{
    int t = blockIdx.x * 256 + threadIdx.x;
    if (t < 768 * 768) {
        int cc = t / 768, d = t % 768;
        float w;
        if (cc < 256)      w = WQ[((size_t)(cc >> 4) * DM + d) * 16 + (cc & 15)];
        else if (cc < 512) w = WK[((size_t)((cc - 256) >> 4) * DM + d) * 16 + (cc & 15)];
        else               w = WV[(size_t)(cc - 512) * DM + d];
        Wqkv_t[t] = tobf(w);
    } else if (t < 768 * 768 + 768 * 256) {
        int u = t - 768 * 768;
        int c = u & 255, m = u >> 8;
        WtO[u] = tobf(WO[(size_t)c * DM + m]);
    } else if (t < 768 * 768 + 768 * 256 + 768) {
        int c = t - (768 * 768 + 768 * 256);
        bqkv[c] = (c < 256) ? bQ[c] : (c < 512 ? bK[c - 256] : bV[c - 512]);
    }
}

// ---------------------------------------------------------------------------
// mm_mfma<KDIM>: C[M=4096][768] = A[4096][KDIM] * Bt[768][KDIM]^T + bias
// ---------------------------------------------------------------------------
template<int KDIM>
__global__ __launch_bounds__(256) void mm_mfma(
    const short* __restrict__ A, const short* __restrict__ Bt,
    const float* __restrict__ bias, float* __restrict__ Cout)
{
    __shared__ short As[128 * 64];
    __shared__ short Bs[64 * 64];

    const int tid  = threadIdx.x;
    const int w    = tid >> 6;
    const int lane = tid & 63;
    const int wm   = w >> 1, wn = w & 1;
    const int g    = lane >> 4, c = lane & 15;
    const int m0   = blockIdx.y * 128;
    const int n0   = blockIdx.x * 64;

    f32x4 acc[4][2];
#pragma unroll
    for (int i = 0; i < 4; ++i)
#pragma unroll
        for (int j = 0; j < 2; ++j) acc[i][j] = (f32x4){0.f, 0.f, 0.f, 0.f};

    const int lr = lane >> 3;
    const int lc = lane & 7;

    for (int k0 = 0; k0 < KDIM; k0 += 64) {
#pragma unroll
        for (int i = 0; i < 4; ++i) {
            const int ch  = i * 4 + w;
            const int row = ch * 8 + lr;
            const int scc = lc ^ (row & 7);
            gload_lds16(A + (size_t)(m0 + row) * KDIM + k0 + scc * 8,
                        As + ch * 512);
        }
#pragma unroll
        for (int i = 0; i < 2; ++i) {
            const int ch  = i * 4 + w;
            const int row = ch * 8 + lr;
            const int scc = lc ^ (row & 7);
            gload_lds16(Bt + (size_t)(n0 + row) * KDIM + k0 + scc * 8,
                        Bs + ch * 512);
        }
        __syncthreads();
#pragma unroll
        for (int kk = 0; kk < 64; kk += 32) {
            short8 af[4], bf[2];
#pragma unroll
            for (int i = 0; i < 4; ++i) {
                const int row = wm * 64 + i * 16 + c;
                const int sc  = ((kk >> 3) + g) ^ (row & 7);
                af[i] = *(const short8*)(As + row * 64 + sc * 8);
            }
#pragma unroll
            for (int j = 0; j < 2; ++j) {
                const int row = wn * 32 + j * 16 + c;
                const int sc  = ((kk >> 3) + g) ^ (row & 7);
                bf[j] = *(const short8*)(Bs + row * 64 + sc * 8);
            }
#pragma unroll
            for (int i = 0; i < 4; ++i)
#pragma unroll
                for (int j = 0; j < 2; ++j)
                    acc[i][j] = __builtin_amdgcn_mfma_f32_16x16x32_bf16(
                        af[i], bf[j], acc[i][j], 0, 0, 0);
        }
        __syncthreads();
    }
#pragma unroll
    for (int i = 0; i < 4; ++i)
#pragma unroll
        for (int j = 0; j < 2; ++j) {
            const int col = n0 + wn * 32 + j * 16 + c;
            const float bv = bias[col];
#pragma unroll
            for (int r = 0; r < 4; ++r) {
                const int row = m0 + wm * 64 + i * 16 + 4 * g + r;
                Cout[(size_t)row * DM + col] = acc[i][j][r] + bv;
            }
        }
}

// ---------------------------------------------------------------------------
// rope_scatter2: rotary + bf16 scatter.
// ---------------------------------------------------------------------------
__global__ __launch_bounds__(256) void rope_scatter2(
    const float* __restrict__ P,
    const float* __restrict__ vK, const float* __restrict__ vV,
    short* __restrict__ Qb, short* __restrict__ Kb, short* __restrict__ Vt)
{
    const int t = blockIdx.x * 256 + threadIdx.x;
    if (t >= 32 * SKP) return;
    const int s  = t % SKP;
    const int bh = t / SKP;
    const int h  = bh & 15;
    const int b  = bh >> 4;

    short kb[16], vb[16];

    if (s < S_) {
        const float* pr = P + (size_t)(b * S_ + s) * DM;
        float qv[16], kv[16], vv[16];
#pragma unroll
        for (int e = 0; e < 16; e += 4) {
            *(float4*)&qv[e] = *(const float4*)(pr + h * 16 + e);
            *(float4*)&kv[e] = *(const float4*)(pr + 256 + h * 16 + e);
            *(float4*)&vv[e] = *(const float4*)(pr + 512 + h * 16 + e);
        }
        const float freqs[8] = {1.0f, 3.1622776601683795f, 10.0f, 31.622776601683793f,
                                100.0f, 316.22776601683796f, 1000.0f, 3162.2776601683795f};
        short qb[16];
#pragma unroll
        for (int e = 0; e < 8; ++e) {
            float ang = (float)s / freqs[e];
            float sn = sinf(ang), cs = cosf(ang);
            float q0 = qv[e] * cs - qv[e + 8] * sn;
            float q1 = qv[e + 8] * cs + qv[e] * sn;
            float k0 = kv[e] * cs - kv[e + 8] * sn;
            float k1 = kv[e + 8] * cs + kv[e] * sn;
            qb[e] = tobf(q0 * QSCALE); qb[e + 8] = tobf(q1 * QSCALE);
            kb[e] = tobf(k0);          kb[e + 8] = tobf(k1);
            vb[e] = tobf(vv[e]);       vb[e + 8] = tobf(vv[e + 8]);
        }
        union { short s[16]; short8 v[2]; } qu;
#pragma unroll
        for (int e = 0; e < 16; ++e) qu.s[e] = qb[e];
        short8* qd = (short8*)(Qb + ((size_t)bh * S_ + s) * 16);
        qd[0] = qu.v[0]; qd[1] = qu.v[1];
    } else if (s < SK) {
        const int tt = s - S_;
#pragma unroll
        for (int e = 0; e < 16; ++e) {
            kb[e] = tobf(vK[(size_t)tt * 256 + h * 16 + e]);
            vb[e] = tobf(vV[(size_t)tt * 256 + h * 16 + e]);
        }
    } else {
#pragma unroll
        for (int e = 0; e < 16; ++e) { kb[e] = 0; vb[e] = 0; }
    }

    union { short s[16]; short8 v[2]; } ku;
#pragma unroll
    for (int e = 0; e < 16; ++e) ku.s[e] = kb[e];
    short8* kd = (short8*)(Kb + ((size_t)bh * SKP + s) * 16);
    kd[0] = ku.v[0]; kd[1] = ku.v[1];
#pragma unroll
    for (int dv = 0; dv < 16; ++dv)
        Vt[((size_t)bh * 16 + dv) * SKP + s] = vb[dv];
}

// ---------------------------------------------------------------------------
// attn_mfma32: 32x32x16-MFMA flash attention, swapped-QK.
//  Wave handles 32 queries. Per 32-key tile:
//   S[32k][32q] = mfma_32x32x16(K_tile, Q_tile)  (K-dim = e = 16, no waste)
//   C/D layout: col(q)=lane&31, row(key)=(reg&3)+8*(reg>>2)+4*hi, hi=lane>>5
//   softmax: per-lane 16-max + shfl_xor(32); P packed via cvt_pk,
//   relayout to PV B-operand via 8x shfl_xor(32) + cndmask.
//   PV: two mfma_32x32x16 (keys 0-15, 16-31), A = V^T rows (dup 16-31).
// ---------------------------------------------------------------------------
__global__ __launch_bounds__(256) void attn_mfma32(
    const short* __restrict__ Qb, const short* __restrict__ Kb,
    const short* __restrict__ Vt, short* __restrict__ Zb)
{
    const int bh   = blockIdx.y;
    const int w    = threadIdx.x >> 6;
    const int lane = threadIdx.x & 63;
    const int hi   = lane >> 5;
    const int qc   = lane & 31;
    // reversed block order: longest waves (high q0) dispatch first
    const int q0   = (int)(gridDim.x - 1 - blockIdx.x) * 128 + w * 32;

    const f32x16 zero16 = {0,0,0,0,0,0,0,0,0,0,0,0,0,0,0,0};

    // Q fragment (B operand): lane holds Q[e=8*hi+i][q0+qc]
    short8 qf = *(const short8*)(Qb + ((size_t)bh * S_ + q0 + qc) * 16 + 8 * hi);

    f32x16 acc = zero16;
    float m = -INFINITY, lsum = 0.f;

    const short* kp = Kb + (size_t)bh * SKP * 16 + (size_t)qc * 16 + 8 * hi;
    const short* vrow = Vt + ((size_t)bh * 16 + (qc & 15)) * SKP + 8 * hi;
    const int qv16 = q0 + qc + 16;
    const int kt_end = q0 + 32;

    for (int kt = 0; kt <= kt_end; kt += 32) {
        // A operand of QK: K[key=qc (+kt)][e=8hi+i]
        short8 kf = *(const short8*)(kp + (size_t)kt * 16);
        // A operands of PV: V^T[dv=qc&15][key = kt(+16) + 8hi + i]
        short8 va = *(const short8*)(vrow + kt);
        short8 vb = *(const short8*)(vrow + kt + 16);

        f32x16 S = __builtin_amdgcn_mfma_f32_32x32x16_bf16(kf, qf, zero16, 0, 0, 0);

        if (kt + 31 > q0 + 16) {   // wave-uniform: tile not fully visible
#pragma unroll
            for (int r = 0; r < 16; ++r) {
                const int key = kt + (r & 3) + 8 * (r >> 2) + 4 * hi;
                S[r] = (key <= qv16) ? S[r] : -INFINITY;
            }
        }
        // row max over this lane's 16 keys, then combine with partner lane
        float tm = fmaxf(
            fmaxf(fmaxf(fmaxf(S[0], S[1]), fmaxf(S[2], S[3])),
                  fmaxf(fmaxf(S[4], S[5]), fmaxf(S[6], S[7]))),
            fmaxf(fmaxf(fmaxf(S[8], S[9]), fmaxf(S[10], S[11])),
                  fmaxf(fmaxf(S[12], S[13]), fmaxf(S[14], S[15]))));
        tm = fmaxf(tm, __shfl_xor(tm, 32));
        const float mnew = fmaxf(m, tm);
        const float f = __builtin_amdgcn_exp2f(m - mnew);

        // p = exp2(S - mnew), packed in pairs (regs 2j, 2j+1)
        unsigned pk[8];
        float ls = 0.f;
#pragma unroll
        for (int j = 0; j < 8; ++j) {
            const float p0 = __builtin_amdgcn_exp2f(S[2 * j] - mnew);
            const float p1 = __builtin_amdgcn_exp2f(S[2 * j + 1] - mnew);
            ls += p0 + p1;
            asm("v_cvt_pk_bf16_f32 %0, %1, %2" : "=v"(pk[j]) : "v"(p0), "v"(p1));
        }
        lsum = lsum * f + ls;
#pragma unroll
        for (int r = 0; r < 8; ++r) acc[r] *= f;

        // partner lane's packs
        unsigned x0 = (unsigned)__shfl_xor((int)pk[0], 32);
        unsigned x1 = (unsigned)__shfl_xor((int)pk[1], 32);
        unsigned x2 = (unsigned)__shfl_xor((int)pk[2], 32);
        unsigned x3 = (unsigned)__shfl_xor((int)pk[3], 32);
        unsigned x4 = (unsigned)__shfl_xor((int)pk[4], 32);
        unsigned x5 = (unsigned)__shfl_xor((int)pk[5], 32);
        unsigned x6 = (unsigned)__shfl_xor((int)pk[6], 32);
        unsigned x7 = (unsigned)__shfl_xor((int)pk[7], 32);

        // B operand mfma1 (keys kt..kt+15): lane needs P[kt+8hi+i][qc]
        //  lo: (0,1)(2,3)(4,5)(6,7) = pk0,pk1,x0,x1
        //  hi: (8,9)(10,11)(12,13)(14,15) = x2,x3,pk2,pk3
        union { unsigned u[4]; short8 v; } b1, b2;
        b1.u[0] = hi ? x2 : pk[0];
        b1.u[1] = hi ? x3 : pk[1];
        b1.u[2] = hi ? pk[2] : x0;
        b1.u[3] = hi ? pk[3] : x1;
        // B operand mfma2 (keys kt+16..kt+31)
        b2.u[0] = hi ? x6 : pk[4];
        b2.u[1] = hi ? x7 : pk[5];
        b2.u[2] = hi ? pk[6] : x4;
        b2.u[3] = hi ? pk[7] : x5;

        acc = __builtin_amdgcn_mfma_f32_32x32x16_bf16(va, b1.v, acc, 0, 0, 0);
        acc = __builtin_amdgcn_mfma_f32_32x32x16_bf16(vb, b2.v, acc, 0, 0, 0);
        m = mnew;
    }

    lsum += __shfl_xor(lsum, 32);
    const float inv = 1.f / lsum;

    // acc regs 0..7 hold O[dv = (r&3)+8*(r>>2)+4*hi][q = q0+qc]
    const int b = bh >> 4, h = bh & 15;
    short* zp = Zb + ((size_t)(b * S_ + q0 + qc)) * C_ + h * 16;
    unsigned o01, o23, o45, o67;
    {
        float a0 = acc[0] * inv, a1 = acc[1] * inv, a2 = acc[2] * inv, a3 = acc[3] * inv;
        float a4 = acc[4] * inv, a5 = acc[5] * inv, a6 = acc[6] * inv, a7 = acc[7] * inv;
        asm("v_cvt_pk_bf16_f32 %0, %1, %2" : "=v"(o01) : "v"(a0), "v"(a1));
        asm("v_cvt_pk_bf16_f32 %0, %1, %2" : "=v"(o23) : "v"(a2), "v"(a3));
        asm("v_cvt_pk_bf16_f32 %0, %1, %2" : "=v"(o45) : "v"(a4), "v"(a5));
        asm("v_cvt_pk_bf16_f32 %0, %1, %2" : "=v"(o67) : "v"(a6), "v"(a7));
    }
    *(unsigned*)(zp + 4 * hi)     = o01;   // dv 4hi, 4hi+1
    *(unsigned*)(zp + 4 * hi + 2) = o23;   // dv 4hi+2, 4hi+3
    *(unsigned*)(zp + 8 + 4 * hi)     = o45;
    *(unsigned*)(zp + 8 + 4 * hi + 2) = o67;
}

extern "C" void kernel_launch(void* const* d_in, const int* in_sizes, int n_in,
                              void* d_out, int out_size, void* d_ws, size_t ws_size,
                              hipStream_t stream)
{
    const float* resid = (const float*)d_in[0];
    const float* WQ = (const float*)d_in[1];
    const float* WK = (const float*)d_in[2];
    const float* WV = (const float*)d_in[3];
    const float* WO = (const float*)d_in[4];
    const float* bQ = (const float*)d_in[5];
    const float* bK = (const float*)d_in[6];
    const float* bV = (const float*)d_in[7];
    const float* bO = (const float*)d_in[8];
    const float* vK = (const float*)d_in[9];
    const float* vV = (const float*)d_in[10];
    float* out = (float*)d_out;
    float* ws  = (float*)d_ws;

    float* P    = ws;                               // 3,145,728 f32
    float* bqkv = ws + 3145728;                     // 768 f32
    short* Ab   = (short*)(ws + 3145728 + 768);     // 3,145,728 bf16
    short* Wqt  = Ab + 3145728;                     // 589,824
    short* WtO  = Wqt + 589824;                     // 196,608
    short* Qb   = WtO + 196608;                     // 1,048,576
    short* Kb   = Qb + 1048576;                     // 1,064,960
    short* Vt   = Kb + 1064960;                     // 1,064,960
    short* Zb   = (short*)ws;                       // aliases P (dead after rope)

    conv_bf16<<<dim3(3072), 256, 0, stream>>>(resid, Ab, 4096 * 768);
    conv_weights<<<dim3(3075), 256, 0, stream>>>(WQ, WK, WV, WO, bQ, bK, bV,
                                                 Wqt, bqkv, WtO);
    mm_mfma<768><<<dim3(12, 32), 256, 0, stream>>>(Ab, Wqt, bqkv, P);
    rope_scatter2<<<dim3((32 * SKP + 255) / 256), 256, 0, stream>>>(P, vK, vV, Qb, Kb, Vt);
    attn_mfma32<<<dim3(16, 32), 256, 0, stream>>>(Qb, Kb, Vt, Zb);
    mm_mfma<256><<<dim3(12, 32), 256, 0, stream>>>(Zb, WtO, bO, out);
}

// Round 5
// 82.163 us; speedup vs baseline: 5.3550x; 1.1707x over previous
//
#include <hip/hip_runtime.h>
#include <hip/hip_bf16.h>
#include <math.h>

// Problem constants
#define B_   2
#define S_   2048
#define DM   768
#define H_   16      // N_QK
#define C_   256     // N_OV
#define VKV_ 16
#define SK   2064    // S_ + VKV_
#define SKP  2080    // padded to multiple of 32 (rows >=2064 zeroed)

#define TSPLIT 22    // key-tiles per split; ns = ceil((qt+2)/22) <= 3

typedef __attribute__((ext_vector_type(8))) short short8;    // 8 bf16
typedef __attribute__((ext_vector_type(4))) short short4v;
typedef __attribute__((ext_vector_type(4))) float f32x4;
typedef __attribute__((ext_vector_type(16))) float f32x16;
typedef __attribute__((ext_vector_type(4))) unsigned uint4v;

// log2(e) / SCALE folded into Q so p = exp2(s)   [no max subtraction: |s| ~ 1]
#define QSCALE 0.360673760222240851f

__device__ __forceinline__ short tobf(float f) {
    union { float f; unsigned u; } x; x.f = f;
    unsigned r = x.u + 0x7FFFu + ((x.u >> 16) & 1u);   // RNE
    return (short)(r >> 16);
}
__device__ __forceinline__ float frombf_lo(unsigned u) {
    union { unsigned u; float f; } x; x.u = u << 16; return x.f;
}
__device__ __forceinline__ float frombf_hi(unsigned u) {
    union { unsigned u; float f; } x; x.u = u & 0xFFFF0000u; return x.f;
}

__device__ __forceinline__ void gload_lds16(const short* g, short* l) {
    __builtin_amdgcn_global_load_lds(
        (const __attribute__((address_space(1))) unsigned int*)g,
        (__attribute__((address_space(3))) unsigned int*)l, 16, 0, 0);
}

// ---------------------------------------------------------------------------
// conv_bf16: fp32 -> bf16, 4 elements/thread
// ---------------------------------------------------------------------------
__global__ __launch_bounds__(256) void conv_bf16(
    const float* __restrict__ in, short* __restrict__ out, int n)
{
    int t = (blockIdx.x * 256 + threadIdx.x) * 4;
    if (t >= n) return;
    float4 v = *(const float4*)(in + t);
    short4v o = { tobf(v.x), tobf(v.y), tobf(v.z), tobf(v.w) };
    *(short4v*)(out + t) = o;
}

// ---------------------------------------------------------------------------
// conv_weights: pack Wqkv_t [768 c][768 d] bf16, bqkv[768] f32, WtO [768 m][256 c]
// ---------------------------------------------------------------------------
__global__ __launch_bounds__(256) void conv_weights(
    const float* __restrict__ WQ, const float* __restrict__ WK,
    const float* __restrict__ WV, const float* __restrict__ WO,
    const float* __restrict__ bQ, const float* __restrict__ bK,
    const float* __restrict__ bV,
    short* __restrict__ Wqkv_t, float* __restrict__ bqkv, short* __restrict__ WtO)
{
    int t = blockIdx.x * 256 + threadIdx.x;
    if (t < 768 * 768) {
        int cc = t / 768, d = t % 768;
        float w;
        if (cc < 256)      w = WQ[((size_t)(cc >> 4) * DM + d) * 16 + (cc & 15)];
        else if (cc < 512) w = WK[((size_t)((cc - 256) >> 4) * DM + d) * 16 + (cc & 15)];
        else               w = WV[(size_t)(cc - 512) * DM + d];
        Wqkv_t[t] = tobf(w);
    } else if (t < 768 * 768 + 768 * 256) {
        int u = t - 768 * 768;
        int c = u & 255, m = u >> 8;
        WtO[u] = tobf(WO[(size_t)c * DM + m]);
    } else if (t < 768 * 768 + 768 * 256 + 768) {
        int c = t - (768 * 768 + 768 * 256);
        bqkv[c] = (c < 256) ? bQ[c] : (c < 512 ? bK[c - 256] : bV[c - 512]);
    }
}

// ---------------------------------------------------------------------------
// mm_mfma<KDIM>: C[M=4096][768] = A[4096][KDIM] * Bt[768][KDIM]^T + bias
// ---------------------------------------------------------------------------
template<int KDIM>
__global__ __launch_bounds__(256) void mm_mfma(
    const short* __restrict__ A, const short* __restrict__ Bt,
    const float* __restrict__ bias, float* __restrict__ Cout)
{
    __shared__ short As[128 * 64];
    __shared__ short Bs[64 * 64];

    const int tid  = threadIdx.x;
    const int w    = tid >> 6;
    const int lane = tid & 63;
    const int wm   = w >> 1, wn = w & 1;
    const int g    = lane >> 4, c = lane & 15;
    const int m0   = blockIdx.y * 128;
    const int n0   = blockIdx.x * 64;

    f32x4 acc[4][2];
#pragma unroll
    for (int i = 0; i < 4; ++i)
#pragma unroll
        for (int j = 0; j < 2; ++j) acc[i][j] = (f32x4){0.f, 0.f, 0.f, 0.f};

    const int lr = lane >> 3;
    const int lc = lane & 7;

    for (int k0 = 0; k0 < KDIM; k0 += 64) {
#pragma unroll
        for (int i = 0; i < 4; ++i) {
            const int ch  = i * 4 + w;
            const int row = ch * 8 + lr;
            const int scc = lc ^ (row & 7);
            gload_lds16(A + (size_t)(m0 + row) * KDIM + k0 + scc * 8,
                        As + ch * 512);
        }
#pragma unroll
        for (int i = 0; i < 2; ++i) {
            const int ch  = i * 4 + w;
            const int row = ch * 8 + lr;
            const int scc = lc ^ (row & 7);
            gload_lds16(Bt + (size_t)(n0 + row) * KDIM + k0 + scc * 8,
                        Bs + ch * 512);
        }
        __syncthreads();
#pragma unroll
        for (int kk = 0; kk < 64; kk += 32) {
            short8 af[4], bf[2];
#pragma unroll
            for (int i = 0; i < 4; ++i) {
                const int row = wm * 64 + i * 16 + c;
                const int sc  = ((kk >> 3) + g) ^ (row & 7);
                af[i] = *(const short8*)(As + row * 64 + sc * 8);
            }
#pragma unroll
            for (int j = 0; j < 2; ++j) {
                const int row = wn * 32 + j * 16 + c;
                const int sc  = ((kk >> 3) + g) ^ (row & 7);
                bf[j] = *(const short8*)(Bs + row * 64 + sc * 8);
            }
#pragma unroll
            for (int i = 0; i < 4; ++i)
#pragma unroll
                for (int j = 0; j < 2; ++j)
                    acc[i][j] = __builtin_amdgcn_mfma_f32_16x16x32_bf16(
                        af[i], bf[j], acc[i][j], 0, 0, 0);
        }
        __syncthreads();
    }
#pragma unroll
    for (int i = 0; i < 4; ++i)
#pragma unroll
        for (int j = 0; j < 2; ++j) {
            const int col = n0 + wn * 32 + j * 16 + c;
            const float bv = bias[col];
#pragma unroll
            for (int r = 0; r < 4; ++r) {
                const int row = m0 + wm * 64 + i * 16 + 4 * g + r;
                Cout[(size_t)row * DM + col] = acc[i][j][r] + bv;
            }
        }
}

// ---------------------------------------------------------------------------
// rope_scatter2: rotary + bf16 scatter.
// ---------------------------------------------------------------------------
__global__ __launch_bounds__(256) void rope_scatter2(
    const float* __restrict__ P,
    const float* __restrict__ vK, const float* __restrict__ vV,
    short* __restrict__ Qb, short* __restrict__ Kb, short* __restrict__ Vt)
{
    const int t = blockIdx.x * 256 + threadIdx.x;
    if (t >= 32 * SKP) return;
    const int s  = t % SKP;
    const int bh = t / SKP;
    const int h  = bh & 15;
    const int b  = bh >> 4;

    short kb[16], vb[16];

    if (s < S_) {
        const float* pr = P + (size_t)(b * S_ + s) * DM;
        float qv[16], kv[16], vv[16];
#pragma unroll
        for (int e = 0; e < 16; e += 4) {
            *(float4*)&qv[e] = *(const float4*)(pr + h * 16 + e);
            *(float4*)&kv[e] = *(const float4*)(pr + 256 + h * 16 + e);
            *(float4*)&vv[e] = *(const float4*)(pr + 512 + h * 16 + e);
        }
        const float freqs[8] = {1.0f, 3.1622776601683795f, 10.0f, 31.622776601683793f,
                                100.0f, 316.22776601683796f, 1000.0f, 3162.2776601683795f};
        short qb[16];
#pragma unroll
        for (int e = 0; e < 8; ++e) {
            float ang = (float)s / freqs[e];
            float sn = sinf(ang), cs = cosf(ang);
            float q0 = qv[e] * cs - qv[e + 8] * sn;
            float q1 = qv[e + 8] * cs + qv[e] * sn;
            float k0 = kv[e] * cs - kv[e + 8] * sn;
            float k1 = kv[e + 8] * cs + kv[e] * sn;
            qb[e] = tobf(q0 * QSCALE); qb[e + 8] = tobf(q1 * QSCALE);
            kb[e] = tobf(k0);          kb[e + 8] = tobf(k1);
            vb[e] = tobf(vv[e]);       vb[e + 8] = tobf(vv[e + 8]);
        }
        union { short s[16]; short8 v[2]; } qu;
#pragma unroll
        for (int e = 0; e < 16; ++e) qu.s[e] = qb[e];
        short8* qd = (short8*)(Qb + ((size_t)bh * S_ + s) * 16);
        qd[0] = qu.v[0]; qd[1] = qu.v[1];
    } else if (s < SK) {
        const int tt = s - S_;
#pragma unroll
        for (int e = 0; e < 16; ++e) {
            kb[e] = tobf(vK[(size_t)tt * 256 + h * 16 + e]);
            vb[e] = tobf(vV[(size_t)tt * 256 + h * 16 + e]);
        }
    } else {
#pragma unroll
        for (int e = 0; e < 16; ++e) { kb[e] = 0; vb[e] = 0; }
    }

    union { short s[16]; short8 v[2]; } ku;
#pragma unroll
    for (int e = 0; e < 16; ++e) ku.s[e] = kb[e];
    short8* kd = (short8*)(Kb + ((size_t)bh * SKP + s) * 16);
    kd[0] = ku.v[0]; kd[1] = ku.v[1];
#pragma unroll
    for (int dv = 0; dv < 16; ++dv)
        Vt[((size_t)bh * 16 + dv) * SKP + s] = vb[dv];
}

// ---------------------------------------------------------------------------
// attn_split: 32x32x16-MFMA attention, swapped-QK, NO max tracking (scores
//  are O(1): p = exp2(s) directly; softmax is linear -> key-split partials).
//  Wave = (bh, qt, split). Split covers key-tiles [sp*22, min(sp*22+22, qt+2)).
//  Partial out (unnormalized): PartA[(bh*64+qt)*3+sp][lane] = 4 u32 (8 bf16
//  acc, dv per C/D layout), PartL[...][qc] = f32 l (full 32-key row sum).
// ---------------------------------------------------------------------------
__global__ __launch_bounds__(256) void attn_split(
    const short* __restrict__ Qb, const short* __restrict__ Kb,
    const short* __restrict__ Vt, unsigned* __restrict__ PartA,
    float* __restrict__ PartL)
{
    const int w    = threadIdx.x >> 6;
    const int lane = threadIdx.x & 63;
    const int wid  = blockIdx.x * 4 + w;
    const int bh   = wid / 192;
    const int rem  = wid - bh * 192;
    const int qt   = rem / 3;
    const int sp   = rem - qt * 3;

    const int nt = qt + 2;            // key tiles for this q-tile
    const int t0 = sp * TSPLIT;
    if (t0 >= nt) return;             // wave-uniform exit
    const int t1 = min(t0 + TSPLIT, nt);

    const int hi = lane >> 5;
    const int qc = lane & 31;
    const int q0 = qt * 32;

    const f32x16 zero16 = {0,0,0,0,0,0,0,0,0,0,0,0,0,0,0,0};

    short8 qf = *(const short8*)(Qb + ((size_t)bh * S_ + q0 + qc) * 16 + 8 * hi);

    f32x16 acc = zero16;
    float lsum = 0.f;

    const short* kp   = Kb + (size_t)bh * SKP * 16 + (size_t)qc * 16 + 8 * hi;
    const short* vrow = Vt + ((size_t)bh * 16 + (qc & 15)) * SKP + 8 * hi;
    const int qv16 = q0 + qc + 16;
    const int mask_from = q0 - 14;    // kt >= this -> tile needs masking

    for (int kt = t0 * 32; kt < t1 * 32; kt += 32) {
        short8 kf = *(const short8*)(kp + (size_t)kt * 16);
        short8 va = *(const short8*)(vrow + kt);
        short8 vb = *(const short8*)(vrow + kt + 16);

        f32x16 S = __builtin_amdgcn_mfma_f32_32x32x16_bf16(kf, qf, zero16, 0, 0, 0);

        if (kt >= mask_from) {        // wave-uniform branch (last two tiles)
#pragma unroll
            for (int r = 0; r < 16; ++r) {
                const int key = kt + (r & 3) + 8 * (r >> 2) + 4 * hi;
                S[r] = (key <= qv16) ? S[r] : -INFINITY;
            }
        }
        unsigned pk[8];
#pragma unroll
        for (int j = 0; j < 8; ++j) {
            const float p0 = __builtin_amdgcn_exp2f(S[2 * j]);
            const float p1 = __builtin_amdgcn_exp2f(S[2 * j + 1]);
            lsum += p0 + p1;
            asm("v_cvt_pk_bf16_f32 %0, %1, %2" : "=v"(pk[j]) : "v"(p0), "v"(p1));
        }
        unsigned x0 = (unsigned)__shfl_xor((int)pk[0], 32);
        unsigned x1 = (unsigned)__shfl_xor((int)pk[1], 32);
        unsigned x2 = (unsigned)__shfl_xor((int)pk[2], 32);
        unsigned x3 = (unsigned)__shfl_xor((int)pk[3], 32);
        unsigned x4 = (unsigned)__shfl_xor((int)pk[4], 32);
        unsigned x5 = (unsigned)__shfl_xor((int)pk[5], 32);
        unsigned x6 = (unsigned)__shfl_xor((int)pk[6], 32);
        unsigned x7 = (unsigned)__shfl_xor((int)pk[7], 32);

        union { unsigned u[4]; short8 v; } b1, b2;
        b1.u[0] = hi ? x2 : pk[0];
        b1.u[1] = hi ? x3 : pk[1];
        b1.u[2] = hi ? pk[2] : x0;
        b1.u[3] = hi ? pk[3] : x1;
        b2.u[0] = hi ? x6 : pk[4];
        b2.u[1] = hi ? x7 : pk[5];
        b2.u[2] = hi ? pk[6] : x4;
        b2.u[3] = hi ? pk[7] : x5;

        acc = __builtin_amdgcn_mfma_f32_32x32x16_bf16(va, b1.v, acc, 0, 0, 0);
        acc = __builtin_amdgcn_mfma_f32_32x32x16_bf16(vb, b2.v, acc, 0, 0, 0);
    }

    // pack partial acc (regs 0..7 hold all 16 dv) to 4 bf16-pairs, store 16B
    uint4v pa;
    asm("v_cvt_pk_bf16_f32 %0, %1, %2" : "=v"(pa.x) : "v"(acc[0]), "v"(acc[1]));
    asm("v_cvt_pk_bf16_f32 %0, %1, %2" : "=v"(pa.y) : "v"(acc[2]), "v"(acc[3]));
    asm("v_cvt_pk_bf16_f32 %0, %1, %2" : "=v"(pa.z) : "v"(acc[4]), "v"(acc[5]));
    asm("v_cvt_pk_bf16_f32 %0, %1, %2" : "=v"(pa.w) : "v"(acc[6]), "v"(acc[7]));

    const int pidx = (bh * 64 + qt) * 3 + sp;
    *(uint4v*)(PartA + ((size_t)pidx * 64 + lane) * 4) = pa;

    lsum += __shfl_xor(lsum, 32);     // full 32-key row sum for query qc
    if (hi == 0) PartL[(size_t)pidx * 32 + qc] = lsum;
}

// ---------------------------------------------------------------------------
// attn_combine: wave per (bh,qt): sum <=3 partials, normalize, write bf16 Z.
// ---------------------------------------------------------------------------
__global__ __launch_bounds__(256) void attn_combine(
    const unsigned* __restrict__ PartA, const float* __restrict__ PartL,
    short* __restrict__ Zb)
{
    const int w    = threadIdx.x >> 6;
    const int lane = threadIdx.x & 63;
    const int wid  = blockIdx.x * 4 + w;     // 0..2047
    const int bh   = wid >> 6;
    const int qt   = wid & 63;
    const int hi   = lane >> 5;
    const int qc   = lane & 31;
    const int ns   = (qt + 2 + TSPLIT - 1) / TSPLIT;

    float a[8];
#pragma unroll
    for (int r = 0; r < 8; ++r) a[r] = 0.f;
    float lsum = 0.f;

    const int pbase = (bh * 64 + qt) * 3;
    for (int sp = 0; sp < ns; ++sp) {
        uint4v pa = *(const uint4v*)(PartA + ((size_t)(pbase + sp) * 64 + lane) * 4);
        a[0] += frombf_lo(pa.x); a[1] += frombf_hi(pa.x);
        a[2] += frombf_lo(pa.y); a[3] += frombf_hi(pa.y);
        a[4] += frombf_lo(pa.z); a[5] += frombf_hi(pa.z);
        a[6] += frombf_lo(pa.w); a[7] += frombf_hi(pa.w);
        lsum += PartL[(size_t)(pbase + sp) * 32 + qc];
    }
    const float inv = 1.f / lsum;

    const int b = bh >> 4, h = bh & 15;
    const int q0 = qt * 32;
    short* zp = Zb + ((size_t)(b * S_ + q0 + qc)) * C_ + h * 16;
    unsigned o01, o23, o45, o67;
    {
        float a0 = a[0] * inv, a1 = a[1] * inv, a2 = a[2] * inv, a3 = a[3] * inv;
        float a4 = a[4] * inv, a5 = a[5] * inv, a6 = a[6] * inv, a7 = a[7] * inv;
        asm("v_cvt_pk_bf16_f32 %0, %1, %2" : "=v"(o01) : "v"(a0), "v"(a1));
        asm("v_cvt_pk_bf16_f32 %0, %1, %2" : "=v"(o23) : "v"(a2), "v"(a3));
        asm("v_cvt_pk_bf16_f32 %0, %1, %2" : "=v"(o45) : "v"(a4), "v"(a5));
        asm("v_cvt_pk_bf16_f32 %0, %1, %2" : "=v"(o67) : "v"(a6), "v"(a7));
    }
    *(unsigned*)(zp + 4 * hi)         = o01;
    *(unsigned*)(zp + 4 * hi + 2)     = o23;
    *(unsigned*)(zp + 8 + 4 * hi)     = o45;
    *(unsigned*)(zp + 8 + 4 * hi + 2) = o67;
}

extern "C" void kernel_launch(void* const* d_in, const int* in_sizes, int n_in,
                              void* d_out, int out_size, void* d_ws, size_t ws_size,
                              hipStream_t stream)
{
    const float* resid = (const float*)d_in[0];
    const float* WQ = (const float*)d_in[1];
    const float* WK = (const float*)d_in[2];
    const float* WV = (const float*)d_in[3];
    const float* WO = (const float*)d_in[4];
    const float* bQ = (const float*)d_in[5];
    const float* bK = (const float*)d_in[6];
    const float* bV = (const float*)d_in[7];
    const float* bO = (const float*)d_in[8];
    const float* vK = (const float*)d_in[9];
    const float* vV = (const float*)d_in[10];
    float* out = (float*)d_out;
    float* ws  = (float*)d_ws;

    float* P    = ws;                               // 3,145,728 f32
    float* bqkv = ws + 3145728;                     // 768 f32
    short* Ab   = (short*)(ws + 3145728 + 768);     // 3,145,728 bf16
    short* Wqt  = Ab + 3145728;                     // 589,824
    short* WtO  = Wqt + 589824;                     // 196,608
    short* Qb   = WtO + 196608;                     // 1,048,576
    short* Kb   = Qb + 1048576;                     // 1,064,960
    short* Vt   = Kb + 1064960;                     // 1,064,960
    short* Zb   = (short*)ws;                       // aliases P (dead after rope)
    // Partials alias Ab (dead after mm768) and Wqt (dead after mm768):
    unsigned* PartA = (unsigned*)Ab;                // 32*64*3*64*4 u32 = 6.29 MB
    float*    PartL = (float*)Wqt;                  // 32*64*3*32 f32 = 786 KB

    conv_bf16<<<dim3(3072), 256, 0, stream>>>(resid, Ab, 4096 * 768);
    conv_weights<<<dim3(3075), 256, 0, stream>>>(WQ, WK, WV, WO, bQ, bK, bV,
                                                 Wqt, bqkv, WtO);
    mm_mfma<768><<<dim3(12, 32), 256, 0, stream>>>(Ab, Wqt, bqkv, P);
    rope_scatter2<<<dim3((32 * SKP + 255) / 256), 256, 0, stream>>>(P, vK, vV, Qb, Kb, Vt);
    attn_split<<<dim3(1536), 256, 0, stream>>>(Qb, Kb, Vt, PartA, PartL);
    attn_combine<<<dim3(512), 256, 0, stream>>>(PartA, PartL, Zb);
    mm_mfma<256><<<dim3(12, 32), 256, 0, stream>>>(Zb, WtO, bO, out);
}

// Round 6
// 82.106 us; speedup vs baseline: 5.3587x; 1.0007x over previous
//
#include <hip/hip_runtime.h>
#include <hip/hip_bf16.h>
#include <math.h>

// Problem constants
#define B_   2
#define S_   2048
#define DM   768
#define H_   16      // N_QK
#define C_   256     // N_OV
#define VKV_ 16
#define SK   2064    // S_ + VKV_
#define SKP  2080    // padded to multiple of 32 (rows >=2064 zeroed)

#define TSPLIT 8     // key-tiles per split
#define MAXSP  9     // ceil(66/8)

typedef __attribute__((ext_vector_type(8))) short short8;    // 8 bf16
typedef __attribute__((ext_vector_type(4))) short short4v;
typedef __attribute__((ext_vector_type(4))) float f32x4;
typedef __attribute__((ext_vector_type(16))) float f32x16;
typedef __attribute__((ext_vector_type(4))) unsigned uint4v;

// log2(e) / SCALE folded into Q so p = exp2(s)   [no max subtraction: |s| ~ 1]
#define QSCALE 0.360673760222240851f

__device__ __forceinline__ short tobf(float f) {
    union { float f; unsigned u; } x; x.f = f;
    unsigned r = x.u + 0x7FFFu + ((x.u >> 16) & 1u);   // RNE
    return (short)(r >> 16);
}
__device__ __forceinline__ float frombf_lo(unsigned u) {
    union { unsigned u; float f; } x; x.u = u << 16; return x.f;
}
__device__ __forceinline__ float frombf_hi(unsigned u) {
    union { unsigned u; float f; } x; x.u = u & 0xFFFF0000u; return x.f;
}

__device__ __forceinline__ void gload_lds16(const short* g, short* l) {
    __builtin_amdgcn_global_load_lds(
        (const __attribute__((address_space(1))) unsigned int*)g,
        (__attribute__((address_space(3))) unsigned int*)l, 16, 0, 0);
}

// ---------------------------------------------------------------------------
// conv_bf16: fp32 -> bf16, 4 elements/thread
// ---------------------------------------------------------------------------
__global__ __launch_bounds__(256) void conv_bf16(
    const float* __restrict__ in, short* __restrict__ out, int n)
{
    int t = (blockIdx.x * 256 + threadIdx.x) * 4;
    if (t >= n) return;
    float4 v = *(const float4*)(in + t);
    short4v o = { tobf(v.x), tobf(v.y), tobf(v.z), tobf(v.w) };
    *(short4v*)(out + t) = o;
}

// ---------------------------------------------------------------------------
// fill_ones: Vt rows 16..31 of each bh = bf16 1.0 (PV lsum trick)
// ---------------------------------------------------------------------------
__global__ __launch_bounds__(256) void fill_ones(short* __restrict__ Vt)
{
    const int t = blockIdx.x * 256 + threadIdx.x;   // 8 shorts each
    const int per_bh = 16 * SKP / 8;                // 4160
    if (t >= 32 * per_bh) return;
    const int bh = t / per_bh;
    const int r  = t - bh * per_bh;
    const short one = (short)0x3F80;
    short8 ones = { one, one, one, one, one, one, one, one };
    *(short8*)(Vt + ((size_t)bh * 32 + 16) * SKP + (size_t)r * 8) = ones;
}

// ---------------------------------------------------------------------------
// conv_weights: pack Wqkv_t [768 c][768 d] bf16, bqkv[768] f32, WtO [768 m][256 c]
// ---------------------------------------------------------------------------
__global__ __launch_bounds__(256) void conv_weights(
    const float* __restrict__ WQ, const float* __restrict__ WK,
    const float* __restrict__ WV, const float* __restrict__ WO,
    const float* __restrict__ bQ, const float* __restrict__ bK,
    const float* __restrict__ bV,
    short* __restrict__ Wqkv_t, float* __restrict__ bqkv, short* __restrict__ WtO)
{
    int t = blockIdx.x * 256 + threadIdx.x;
    if (t < 768 * 768) {
        int cc = t / 768, d = t % 768;
        float w;
        if (cc < 256)      w = WQ[((size_t)(cc >> 4) * DM + d) * 16 + (cc & 15)];
        else if (cc < 512) w = WK[((size_t)((cc - 256) >> 4) * DM + d) * 16 + (cc & 15)];
        else               w = WV[(size_t)(cc - 512) * DM + d];
        Wqkv_t[t] = tobf(w);
    } else if (t < 768 * 768 + 768 * 256) {
        int u = t - 768 * 768;
        int c = u & 255, m = u >> 8;
        WtO[u] = tobf(WO[(size_t)c * DM + m]);
    } else if (t < 768 * 768 + 768 * 256 + 768) {
        int c = t - (768 * 768 + 768 * 256);
        bqkv[c] = (c < 256) ? bQ[c] : (c < 512 ? bK[c - 256] : bV[c - 512]);
    }
}

// ---------------------------------------------------------------------------
// mm_mfma<KDIM>: C[M=4096][768] = A[4096][KDIM] * Bt[768][KDIM]^T + bias
// ---------------------------------------------------------------------------
template<int KDIM>
__global__ __launch_bounds__(256) void mm_mfma(
    const short* __restrict__ A, const short* __restrict__ Bt,
    const float* __restrict__ bias, float* __restrict__ Cout)
{
    __shared__ short As[128 * 64];
    __shared__ short Bs[64 * 64];

    const int tid  = threadIdx.x;
    const int w    = tid >> 6;
    const int lane = tid & 63;
    const int wm   = w >> 1, wn = w & 1;
    const int g    = lane >> 4, c = lane & 15;
    const int m0   = blockIdx.y * 128;
    const int n0   = blockIdx.x * 64;

    f32x4 acc[4][2];
#pragma unroll
    for (int i = 0; i < 4; ++i)
#pragma unroll
        for (int j = 0; j < 2; ++j) acc[i][j] = (f32x4){0.f, 0.f, 0.f, 0.f};

    const int lr = lane >> 3;
    const int lc = lane & 7;

    for (int k0 = 0; k0 < KDIM; k0 += 64) {
#pragma unroll
        for (int i = 0; i < 4; ++i) {
            const int ch  = i * 4 + w;
            const int row = ch * 8 + lr;
            const int scc = lc ^ (row & 7);
            gload_lds16(A + (size_t)(m0 + row) * KDIM + k0 + scc * 8,
                        As + ch * 512);
        }
#pragma unroll
        for (int i = 0; i < 2; ++i) {
            const int ch  = i * 4 + w;
            const int row = ch * 8 + lr;
            const int scc = lc ^ (row & 7);
            gload_lds16(Bt + (size_t)(n0 + row) * KDIM + k0 + scc * 8,
                        Bs + ch * 512);
        }
        __syncthreads();
#pragma unroll
        for (int kk = 0; kk < 64; kk += 32) {
            short8 af[4], bf[2];
#pragma unroll
            for (int i = 0; i < 4; ++i) {
                const int row = wm * 64 + i * 16 + c;
                const int sc  = ((kk >> 3) + g) ^ (row & 7);
                af[i] = *(const short8*)(As + row * 64 + sc * 8);
            }
#pragma unroll
            for (int j = 0; j < 2; ++j) {
                const int row = wn * 32 + j * 16 + c;
                const int sc  = ((kk >> 3) + g) ^ (row & 7);
                bf[j] = *(const short8*)(Bs + row * 64 + sc * 8);
            }
#pragma unroll
            for (int i = 0; i < 4; ++i)
#pragma unroll
                for (int j = 0; j < 2; ++j)
                    acc[i][j] = __builtin_amdgcn_mfma_f32_16x16x32_bf16(
                        af[i], bf[j], acc[i][j], 0, 0, 0);
        }
        __syncthreads();
    }
#pragma unroll
    for (int i = 0; i < 4; ++i)
#pragma unroll
        for (int j = 0; j < 2; ++j) {
            const int col = n0 + wn * 32 + j * 16 + c;
            const float bv = bias[col];
#pragma unroll
            for (int r = 0; r < 4; ++r) {
                const int row = m0 + wm * 64 + i * 16 + 4 * g + r;
                Cout[(size_t)row * DM + col] = acc[i][j][r] + bv;
            }
        }
}

// ---------------------------------------------------------------------------
// rope_scatter2: rotary + bf16 scatter.  Vt now [bh][32 rows][SKP]
//  (rows 0-15 = V^T, rows 16-31 pre-filled with 1.0 by fill_ones).
// ---------------------------------------------------------------------------
__global__ __launch_bounds__(256) void rope_scatter2(
    const float* __restrict__ P,
    const float* __restrict__ vK, const float* __restrict__ vV,
    short* __restrict__ Qb, short* __restrict__ Kb, short* __restrict__ Vt)
{
    const int t = blockIdx.x * 256 + threadIdx.x;
    if (t >= 32 * SKP) return;
    const int s  = t % SKP;
    const int bh = t / SKP;
    const int h  = bh & 15;
    const int b  = bh >> 4;

    short kb[16], vb[16];

    if (s < S_) {
        const float* pr = P + (size_t)(b * S_ + s) * DM;
        float qv[16], kv[16], vv[16];
#pragma unroll
        for (int e = 0; e < 16; e += 4) {
            *(float4*)&qv[e] = *(const float4*)(pr + h * 16 + e);
            *(float4*)&kv[e] = *(const float4*)(pr + 256 + h * 16 + e);
            *(float4*)&vv[e] = *(const float4*)(pr + 512 + h * 16 + e);
        }
        const float freqs[8] = {1.0f, 3.1622776601683795f, 10.0f, 31.622776601683793f,
                                100.0f, 316.22776601683796f, 1000.0f, 3162.2776601683795f};
        short qb[16];
#pragma unroll
        for (int e = 0; e < 8; ++e) {
            float ang = (float)s / freqs[e];
            float sn = sinf(ang), cs = cosf(ang);
            float q0 = qv[e] * cs - qv[e + 8] * sn;
            float q1 = qv[e + 8] * cs + qv[e] * sn;
            float k0 = kv[e] * cs - kv[e + 8] * sn;
            float k1 = kv[e + 8] * cs + kv[e] * sn;
            qb[e] = tobf(q0 * QSCALE); qb[e + 8] = tobf(q1 * QSCALE);
            kb[e] = tobf(k0);          kb[e + 8] = tobf(k1);
            vb[e] = tobf(vv[e]);       vb[e + 8] = tobf(vv[e + 8]);
        }
        union { short s[16]; short8 v[2]; } qu;
#pragma unroll
        for (int e = 0; e < 16; ++e) qu.s[e] = qb[e];
        short8* qd = (short8*)(Qb + ((size_t)bh * S_ + s) * 16);
        qd[0] = qu.v[0]; qd[1] = qu.v[1];
    } else if (s < SK) {
        const int tt = s - S_;
#pragma unroll
        for (int e = 0; e < 16; ++e) {
            kb[e] = tobf(vK[(size_t)tt * 256 + h * 16 + e]);
            vb[e] = tobf(vV[(size_t)tt * 256 + h * 16 + e]);
        }
    } else {
#pragma unroll
        for (int e = 0; e < 16; ++e) { kb[e] = 0; vb[e] = 0; }
    }

    union { short s[16]; short8 v[2]; } ku;
#pragma unroll
    for (int e = 0; e < 16; ++e) ku.s[e] = kb[e];
    short8* kd = (short8*)(Kb + ((size_t)bh * SKP + s) * 16);
    kd[0] = ku.v[0]; kd[1] = ku.v[1];
#pragma unroll
    for (int dv = 0; dv < 16; ++dv)
        Vt[((size_t)bh * 32 + dv) * SKP + s] = vb[dv];
}

// ---------------------------------------------------------------------------
// attn_split: 32x32x16-MFMA attention, no max tracking, key-split partials.
//  Wave = (bh, qt, sp); sp covers key-tiles [sp*8, min(sp*8+8, qt+2)).
//  lsum comes FREE from PV MFMA: Vt rows 16-31 are 1.0, so acc[8] = sum_k p.
//  P relayout uses v_permlane32_swap_b32 (1 instr -> both output words).
// ---------------------------------------------------------------------------
__global__ __launch_bounds__(256) void attn_split(
    const short* __restrict__ Qb, const short* __restrict__ Kb,
    const short* __restrict__ Vt, unsigned* __restrict__ PartA,
    float* __restrict__ PartL)
{
    const int w    = threadIdx.x >> 6;
    const int lane = threadIdx.x & 63;
    const int wid  = blockIdx.x * 4 + w;          // < 32*64*MAXSP
    const int bh   = wid / (64 * MAXSP);
    const int rem  = wid - bh * 64 * MAXSP;
    const int qt   = rem / MAXSP;
    const int sp   = rem - qt * MAXSP;

    const int nt = qt + 2;
    const int t0 = sp * TSPLIT;
    if (t0 >= nt) return;                         // wave-uniform exit
    const int ktend = min(t0 + TSPLIT, nt) * 32;

    const int hi = lane >> 5;
    const int qc = lane & 31;
    const int q0 = qt * 32;

    const f32x16 zero16 = {0,0,0,0,0,0,0,0,0,0,0,0,0,0,0,0};

    short8 qf = *(const short8*)(Qb + ((size_t)bh * S_ + q0 + qc) * 16 + 8 * hi);

    f32x16 acc = zero16;

    const short* kp   = Kb + (size_t)bh * SKP * 16 + (size_t)qc * 16 + 8 * hi;
    const short* vrow = Vt + ((size_t)bh * 32 + qc) * SKP + 8 * hi;  // qc>=16 -> ones
    const int qv16 = q0 + qc + 16;
    const int mask_from = q0 - 14;

    int kt = t0 * 32;
    short8 kf = *(const short8*)(kp + (size_t)kt * 16);

    for (; kt < ktend; kt += 32) {
        short8 kfn = kf;
        if (kt + 32 < ktend)                      // wave-uniform
            kfn = *(const short8*)(kp + (size_t)(kt + 32) * 16);
        short8 va = *(const short8*)(vrow + kt);
        short8 vb = *(const short8*)(vrow + kt + 16);

        f32x16 S = __builtin_amdgcn_mfma_f32_32x32x16_bf16(kf, qf, zero16, 0, 0, 0);

        if (kt >= mask_from) {                    // wave-uniform (last tiles)
#pragma unroll
            for (int r = 0; r < 16; ++r) {
                const int key = kt + (r & 3) + 8 * (r >> 2) + 4 * hi;
                S[r] = (key <= qv16) ? S[r] : -INFINITY;
            }
        }
        unsigned pk[8];
#pragma unroll
        for (int j = 0; j < 8; ++j) {
            const float p0 = __builtin_amdgcn_exp2f(S[2 * j]);
            const float p1 = __builtin_amdgcn_exp2f(S[2 * j + 1]);
            asm("v_cvt_pk_bf16_f32 %0, %1, %2" : "=v"(pk[j]) : "v"(p0), "v"(p1));
        }
        // relayout via permlane32_swap: newD={D.lo,S.lo}, newS={D.hi,S.hi}
        unsigned a0 = pk[0], a2 = pk[2];
        unsigned a1 = pk[1], a3 = pk[3];
        unsigned a4 = pk[4], a6 = pk[6];
        unsigned a5 = pk[5], a7 = pk[7];
        asm("v_permlane32_swap_b32 %0, %1" : "+v"(a0), "+v"(a2));
        asm("v_permlane32_swap_b32 %0, %1" : "+v"(a1), "+v"(a3));
        asm("v_permlane32_swap_b32 %0, %1" : "+v"(a4), "+v"(a6));
        asm("v_permlane32_swap_b32 %0, %1" : "+v"(a5), "+v"(a7));
        union { unsigned u[4]; short8 v; } b1, b2;
        b1.u[0] = a0; b1.u[1] = a1; b1.u[2] = a2; b1.u[3] = a3;
        b2.u[0] = a4; b2.u[1] = a5; b2.u[2] = a6; b2.u[3] = a7;

        acc = __builtin_amdgcn_mfma_f32_32x32x16_bf16(va, b1.v, acc, 0, 0, 0);
        acc = __builtin_amdgcn_mfma_f32_32x32x16_bf16(vb, b2.v, acc, 0, 0, 0);
        kf = kfn;
    }

    uint4v pa;
    asm("v_cvt_pk_bf16_f32 %0, %1, %2" : "=v"(pa.x) : "v"(acc[0]), "v"(acc[1]));
    asm("v_cvt_pk_bf16_f32 %0, %1, %2" : "=v"(pa.y) : "v"(acc[2]), "v"(acc[3]));
    asm("v_cvt_pk_bf16_f32 %0, %1, %2" : "=v"(pa.z) : "v"(acc[4]), "v"(acc[5]));
    asm("v_cvt_pk_bf16_f32 %0, %1, %2" : "=v"(pa.w) : "v"(acc[6]), "v"(acc[7]));

    const int pidx = (bh * 64 + qt) * MAXSP + sp;
    *(uint4v*)(PartA + ((size_t)pidx * 64 + lane) * 4) = pa;
    if (hi == 0) PartL[(size_t)pidx * 32 + qc] = acc[8];   // row16 = sum_k p
}

// ---------------------------------------------------------------------------
// attn_combine: wave per (bh,qt): sum <=MAXSP partials, normalize, write Z.
// ---------------------------------------------------------------------------
__global__ __launch_bounds__(256) void attn_combine(
    const unsigned* __restrict__ PartA, const float* __restrict__ PartL,
    short* __restrict__ Zb)
{
    const int w    = threadIdx.x >> 6;
    const int lane = threadIdx.x & 63;
    const int wid  = blockIdx.x * 4 + w;     // 0..2047
    const int bh   = wid >> 6;
    const int qt   = wid & 63;
    const int hi   = lane >> 5;
    const int qc   = lane & 31;
    const int ns   = (qt + 2 + TSPLIT - 1) / TSPLIT;

    float a[8];
#pragma unroll
    for (int r = 0; r < 8; ++r) a[r] = 0.f;
    float lsum = 0.f;

    const int pbase = (bh * 64 + qt) * MAXSP;
    for (int sp = 0; sp < ns; ++sp) {
        uint4v pa = *(const uint4v*)(PartA + ((size_t)(pbase + sp) * 64 + lane) * 4);
        a[0] += frombf_lo(pa.x); a[1] += frombf_hi(pa.x);
        a[2] += frombf_lo(pa.y); a[3] += frombf_hi(pa.y);
        a[4] += frombf_lo(pa.z); a[5] += frombf_hi(pa.z);
        a[6] += frombf_lo(pa.w); a[7] += frombf_hi(pa.w);
        lsum += PartL[(size_t)(pbase + sp) * 32 + qc];
    }
    const float inv = 1.f / lsum;

    const int b = bh >> 4, h = bh & 15;
    const int q0 = qt * 32;
    short* zp = Zb + ((size_t)(b * S_ + q0 + qc)) * C_ + h * 16;
    unsigned o01, o23, o45, o67;
    {
        float a0 = a[0] * inv, a1 = a[1] * inv, a2 = a[2] * inv, a3 = a[3] * inv;
        float a4 = a[4] * inv, a5 = a[5] * inv, a6 = a[6] * inv, a7 = a[7] * inv;
        asm("v_cvt_pk_bf16_f32 %0, %1, %2" : "=v"(o01) : "v"(a0), "v"(a1));
        asm("v_cvt_pk_bf16_f32 %0, %1, %2" : "=v"(o23) : "v"(a2), "v"(a3));
        asm("v_cvt_pk_bf16_f32 %0, %1, %2" : "=v"(o45) : "v"(a4), "v"(a5));
        asm("v_cvt_pk_bf16_f32 %0, %1, %2" : "=v"(o67) : "v"(a6), "v"(a7));
    }
    *(unsigned*)(zp + 4 * hi)         = o01;
    *(unsigned*)(zp + 4 * hi + 2)     = o23;
    *(unsigned*)(zp + 8 + 4 * hi)     = o45;
    *(unsigned*)(zp + 8 + 4 * hi + 2) = o67;
}

extern "C" void kernel_launch(void* const* d_in, const int* in_sizes, int n_in,
                              void* d_out, int out_size, void* d_ws, size_t ws_size,
                              hipStream_t stream)
{
    const float* resid = (const float*)d_in[0];
    const float* WQ = (const float*)d_in[1];
    const float* WK = (const float*)d_in[2];
    const float* WV = (const float*)d_in[3];
    const float* WO = (const float*)d_in[4];
    const float* bQ = (const float*)d_in[5];
    const float* bK = (const float*)d_in[6];
    const float* bV = (const float*)d_in[7];
    const float* bO = (const float*)d_in[8];
    const float* vK = (const float*)d_in[9];
    const float* vV = (const float*)d_in[10];
    float* out = (float*)d_out;
    float* ws  = (float*)d_ws;

    float* P    = ws;                               // 3,145,728 f32
    float* bqkv = ws + 3145728;                     // 768 f32
    short* Ab   = (short*)(ws + 3145728 + 768);     // 3,145,728 bf16
    short* Wqt  = Ab + 3145728;                     // 589,824
    short* WtO  = Wqt + 589824;                     // 196,608
    short* Qb   = WtO + 196608;                     // 1,048,576
    short* Kb   = Qb + 1048576;                     // 1,064,960 (32*2080*16)
    short* Vt   = Kb + 1064960;                     // 2,129,920 (32*32*2080)
    unsigned* PartA = (unsigned*)(Vt + 2129920);    // 18432*64*4 u32 = 18.9 MB
    float*    PartL = (float*)(PartA + 4718592);    // 18432*32 f32
    short* Zb   = (short*)ws;                       // aliases P (dead after rope)

    conv_bf16<<<dim3(3072), 256, 0, stream>>>(resid, Ab, 4096 * 768);
    fill_ones<<<dim3(520), 256, 0, stream>>>(Vt);
    conv_weights<<<dim3(3075), 256, 0, stream>>>(WQ, WK, WV, WO, bQ, bK, bV,
                                                 Wqt, bqkv, WtO);
    mm_mfma<768><<<dim3(12, 32), 256, 0, stream>>>(Ab, Wqt, bqkv, P);
    rope_scatter2<<<dim3((32 * SKP + 255) / 256), 256, 0, stream>>>(P, vK, vV, Qb, Kb, Vt);
    attn_split<<<dim3(32 * 64 * MAXSP / 4), 256, 0, stream>>>(Qb, Kb, Vt, PartA, PartL);
    attn_combine<<<dim3(512), 256, 0, stream>>>(PartA, PartL, Zb);
    mm_mfma<256><<<dim3(12, 32), 256, 0, stream>>>(Zb, WtO, bO, out);
}

// Round 7
// 79.459 us; speedup vs baseline: 5.5373x; 1.0333x over previous
//
#include <hip/hip_runtime.h>
#include <hip/hip_bf16.h>
#include <math.h>

// Problem constants
#define B_   2
#define S_   2048
#define DM   768
#define H_   16      // N_QK
#define C_   256     // N_OV
#define VKV_ 16
#define SK   2064    // S_ + VKV_
#define SKP  2080    // padded to multiple of 32 (rows >=2064 zeroed)
#define NT_  65      // key tiles per bh (SKP/32)

#define TSPLIT 16    // key-tiles per split
#define MAXSP  5     // ceil(65/16)

typedef __attribute__((ext_vector_type(8))) short short8;    // 8 bf16
typedef __attribute__((ext_vector_type(4))) short short4v;
typedef __attribute__((ext_vector_type(4))) float f32x4;
typedef __attribute__((ext_vector_type(16))) float f32x16;
typedef __attribute__((ext_vector_type(4))) unsigned uint4v;

// log2(e) / SCALE folded into Q so p = exp2(s)   [no max subtraction: |s| ~ 1]
#define QSCALE 0.360673760222240851f

__device__ __forceinline__ short tobf(float f) {
    union { float f; unsigned u; } x; x.f = f;
    unsigned r = x.u + 0x7FFFu + ((x.u >> 16) & 1u);   // RNE
    return (short)(r >> 16);
}
__device__ __forceinline__ float frombf_lo(unsigned u) {
    union { unsigned u; float f; } x; x.u = u << 16; return x.f;
}
__device__ __forceinline__ float frombf_hi(unsigned u) {
    union { unsigned u; float f; } x; x.u = u & 0xFFFF0000u; return x.f;
}

__device__ __forceinline__ void gload_lds16(const short* g, short* l) {
    __builtin_amdgcn_global_load_lds(
        (const __attribute__((address_space(1))) unsigned int*)g,
        (__attribute__((address_space(3))) unsigned int*)l, 16, 0, 0);
}

// ---------------------------------------------------------------------------
// conv_bf16: fp32 -> bf16, 4 elements/thread
// ---------------------------------------------------------------------------
__global__ __launch_bounds__(256) void conv_bf16(
    const float* __restrict__ in, short* __restrict__ out, int n)
{
    int t = (blockIdx.x * 256 + threadIdx.x) * 4;
    if (t >= n) return;
    float4 v = *(const float4*)(in + t);
    short4v o = { tobf(v.x), tobf(v.y), tobf(v.z), tobf(v.w) };
    *(short4v*)(out + t) = o;
}

// ---------------------------------------------------------------------------
// conv_weights: pack Wqkv_t [768 c][768 d] bf16, bqkv[768] f32, WtO [768 m][256 c]
// ---------------------------------------------------------------------------
__global__ __launch_bounds__(256) void conv_weights(
    const float* __restrict__ WQ, const float* __restrict__ WK,
    const float* __restrict__ WV, const float* __restrict__ WO,
    const float* __restrict__ bQ, const float* __restrict__ bK,
    const float* __restrict__ bV,
    short* __restrict__ Wqkv_t, float* __restrict__ bqkv, short* __restrict__ WtO)
{
    int t = blockIdx.x * 256 + threadIdx.x;
    if (t < 768 * 768) {
        int cc = t / 768, d = t % 768;
        float w;
        if (cc < 256)      w = WQ[((size_t)(cc >> 4) * DM + d) * 16 + (cc & 15)];
        else if (cc < 512) w = WK[((size_t)((cc - 256) >> 4) * DM + d) * 16 + (cc & 15)];
        else               w = WV[(size_t)(cc - 512) * DM + d];
        Wqkv_t[t] = tobf(w);
    } else if (t < 768 * 768 + 768 * 256) {
        int u = t - 768 * 768;
        int c = u & 255, m = u >> 8;
        WtO[u] = tobf(WO[(size_t)c * DM + m]);
    } else if (t < 768 * 768 + 768 * 256 + 768) {
        int c = t - (768 * 768 + 768 * 256);
        bqkv[c] = (c < 256) ? bQ[c] : (c < 512 ? bK[c - 256] : bV[c - 512]);
    }
}

// ---------------------------------------------------------------------------
// mm_mfma<KDIM>: C[M=4096][768] = A[4096][KDIM] * Bt[768][KDIM]^T + bias
// ---------------------------------------------------------------------------
template<int KDIM>
__global__ __launch_bounds__(256) void mm_mfma(
    const short* __restrict__ A, const short* __restrict__ Bt,
    const float* __restrict__ bias, float* __restrict__ Cout)
{
    __shared__ short As[128 * 64];
    __shared__ short Bs[64 * 64];

    const int tid  = threadIdx.x;
    const int w    = tid >> 6;
    const int lane = tid & 63;
    const int wm   = w >> 1, wn = w & 1;
    const int g    = lane >> 4, c = lane & 15;
    const int m0   = blockIdx.y * 128;
    const int n0   = blockIdx.x * 64;

    f32x4 acc[4][2];
#pragma unroll
    for (int i = 0; i < 4; ++i)
#pragma unroll
        for (int j = 0; j < 2; ++j) acc[i][j] = (f32x4){0.f, 0.f, 0.f, 0.f};

    const int lr = lane >> 3;
    const int lc = lane & 7;

    for (int k0 = 0; k0 < KDIM; k0 += 64) {
#pragma unroll
        for (int i = 0; i < 4; ++i) {
            const int ch  = i * 4 + w;
            const int row = ch * 8 + lr;
            const int scc = lc ^ (row & 7);
            gload_lds16(A + (size_t)(m0 + row) * KDIM + k0 + scc * 8,
                        As + ch * 512);
        }
#pragma unroll
        for (int i = 0; i < 2; ++i) {
            const int ch  = i * 4 + w;
            const int row = ch * 8 + lr;
            const int scc = lc ^ (row & 7);
            gload_lds16(Bt + (size_t)(n0 + row) * KDIM + k0 + scc * 8,
                        Bs + ch * 512);
        }
        __syncthreads();
#pragma unroll
        for (int kk = 0; kk < 64; kk += 32) {
            short8 af[4], bf[2];
#pragma unroll
            for (int i = 0; i < 4; ++i) {
                const int row = wm * 64 + i * 16 + c;
                const int sc  = ((kk >> 3) + g) ^ (row & 7);
                af[i] = *(const short8*)(As + row * 64 + sc * 8);
            }
#pragma unroll
            for (int j = 0; j < 2; ++j) {
                const int row = wn * 32 + j * 16 + c;
                const int sc  = ((kk >> 3) + g) ^ (row & 7);
                bf[j] = *(const short8*)(Bs + row * 64 + sc * 8);
            }
#pragma unroll
            for (int i = 0; i < 4; ++i)
#pragma unroll
                for (int j = 0; j < 2; ++j)
                    acc[i][j] = __builtin_amdgcn_mfma_f32_16x16x32_bf16(
                        af[i], bf[j], acc[i][j], 0, 0, 0);
        }
        __syncthreads();
    }
#pragma unroll
    for (int i = 0; i < 4; ++i)
#pragma unroll
        for (int j = 0; j < 2; ++j) {
            const int col = n0 + wn * 32 + j * 16 + c;
            const float bv = bias[col];
#pragma unroll
            for (int r = 0; r < 4; ++r) {
                const int row = m0 + wm * 64 + i * 16 + 4 * g + r;
                Cout[(size_t)row * DM + col] = acc[i][j][r] + bv;
            }
        }
}

// ---------------------------------------------------------------------------
// rope_scatter2: rotary + bf16 scatter into per-tile LANE-ORDERED layouts:
//  Qb2[bh][qt][512]: lane l = (qc|hi<<5) holds Q[q0+qc][8*hi..+8]
//  Kb2[bh][t][512] : lane l holds K[kt+qc][8*hi..+8]
//  Vt3[bh][t][1024]: [kh][dv][hi][k7] -> va/vb are contiguous 512B reads
// ---------------------------------------------------------------------------
__global__ __launch_bounds__(256) void rope_scatter2(
    const float* __restrict__ P,
    const float* __restrict__ vK, const float* __restrict__ vV,
    short* __restrict__ Qb2, short* __restrict__ Kb2, short* __restrict__ Vt3)
{
    const int t = blockIdx.x * 256 + threadIdx.x;
    if (t >= 32 * SKP) return;
    const int s  = t % SKP;
    const int bh = t / SKP;
    const int h  = bh & 15;
    const int b  = bh >> 4;

    short kb[16], vb[16];

    if (s < S_) {
        const float* pr = P + (size_t)(b * S_ + s) * DM;
        float qv[16], kv[16], vv[16];
#pragma unroll
        for (int e = 0; e < 16; e += 4) {
            *(float4*)&qv[e] = *(const float4*)(pr + h * 16 + e);
            *(float4*)&kv[e] = *(const float4*)(pr + 256 + h * 16 + e);
            *(float4*)&vv[e] = *(const float4*)(pr + 512 + h * 16 + e);
        }
        const float freqs[8] = {1.0f, 3.1622776601683795f, 10.0f, 31.622776601683793f,
                                100.0f, 316.22776601683796f, 1000.0f, 3162.2776601683795f};
        short qb[16];
#pragma unroll
        for (int e = 0; e < 8; ++e) {
            float ang = (float)s / freqs[e];
            float sn = sinf(ang), cs = cosf(ang);
            float q0 = qv[e] * cs - qv[e + 8] * sn;
            float q1 = qv[e + 8] * cs + qv[e] * sn;
            float k0 = kv[e] * cs - kv[e + 8] * sn;
            float k1 = kv[e + 8] * cs + kv[e] * sn;
            qb[e] = tobf(q0 * QSCALE); qb[e + 8] = tobf(q1 * QSCALE);
            kb[e] = tobf(k0);          kb[e + 8] = tobf(k1);
            vb[e] = tobf(vv[e]);       vb[e + 8] = tobf(vv[e + 8]);
        }
        union { short s[16]; short8 v[2]; } qu;
#pragma unroll
        for (int e = 0; e < 16; ++e) qu.s[e] = qb[e];
        short* qbase = Qb2 + ((size_t)bh * 64 + (s >> 5)) * 512 + (s & 31) * 8;
        *(short8*)qbase         = qu.v[0];
        *(short8*)(qbase + 256) = qu.v[1];
    } else if (s < SK) {
        const int tt = s - S_;
#pragma unroll
        for (int e = 0; e < 16; ++e) {
            kb[e] = tobf(vK[(size_t)tt * 256 + h * 16 + e]);
            vb[e] = tobf(vV[(size_t)tt * 256 + h * 16 + e]);
        }
    } else {
#pragma unroll
        for (int e = 0; e < 16; ++e) { kb[e] = 0; vb[e] = 0; }
    }

    union { short s[16]; short8 v[2]; } ku;
#pragma unroll
    for (int e = 0; e < 16; ++e) ku.s[e] = kb[e];
    const int t5 = s >> 5;
    short* kbase = Kb2 + ((size_t)bh * NT_ + t5) * 512 + (s & 31) * 8;
    *(short8*)kbase         = ku.v[0];
    *(short8*)(kbase + 256) = ku.v[1];

    short* vbase = Vt3 + ((size_t)bh * NT_ + t5) * 1024
                 + ((s >> 4) & 1) * 512 + ((s >> 3) & 1) * 8 + (s & 7);
#pragma unroll
    for (int dv = 0; dv < 16; ++dv)
        vbase[dv * 16] = vb[dv];
}

// ---------------------------------------------------------------------------
// attn_split: 32x32x16-MFMA attention, no max tracking, key-split partials.
//  All hot loads are fully coalesced per-tile lane-ordered blocks (1KB/512B).
// ---------------------------------------------------------------------------
__global__ __launch_bounds__(256) void attn_split(
    const short* __restrict__ Qb2, const short* __restrict__ Kb2,
    const short* __restrict__ Vt3, unsigned* __restrict__ PartA,
    float* __restrict__ PartL)
{
    const int w    = threadIdx.x >> 6;
    const int lane = threadIdx.x & 63;
    const int wid  = blockIdx.x * 4 + w;          // < 32*64*MAXSP
    const int bh   = wid / (64 * MAXSP);
    const int rem  = wid - bh * 64 * MAXSP;
    const int qt   = rem / MAXSP;
    const int sp   = rem - qt * MAXSP;

    const int nt = qt + 2;
    const int t0 = sp * TSPLIT;
    if (t0 >= nt) return;                         // wave-uniform exit
    const int tend = min(t0 + TSPLIT, nt);

    const int hi = lane >> 5;
    const int qc = lane & 31;
    const int q0 = qt * 32;

    const f32x16 zero16 = {0,0,0,0,0,0,0,0,0,0,0,0,0,0,0,0};

    short8 qf = *(const short8*)(Qb2 + ((size_t)bh * 64 + qt) * 512 + lane * 8);

    f32x16 acc = zero16;
    float lsum = 0.f;

    const short* kbase = Kb2 + (size_t)bh * NT_ * 512 + lane * 8;
    const int    voff  = (lane & 15) * 16 + hi * 8;
    const short* vbase = Vt3 + (size_t)bh * NT_ * 1024 + voff;
    const int qv16 = q0 + qc + 16;
    const int tmask = (q0 - 14 + 31) >> 5;        // first tile index needing mask

    int t = t0;
    short8 kf = *(const short8*)(kbase + (size_t)t * 512);
    short8 va = *(const short8*)(vbase + (size_t)t * 1024);
    short8 vv = *(const short8*)(vbase + (size_t)t * 1024 + 512);

    for (; t < tend; ++t) {
        short8 kf_n = kf, va_n = va, vv_n = vv;
        if (t + 1 < tend) {                       // wave-uniform
            kf_n = *(const short8*)(kbase + (size_t)(t + 1) * 512);
            va_n = *(const short8*)(vbase + (size_t)(t + 1) * 1024);
            vv_n = *(const short8*)(vbase + (size_t)(t + 1) * 1024 + 512);
        }

        f32x16 S = __builtin_amdgcn_mfma_f32_32x32x16_bf16(kf, qf, zero16, 0, 0, 0);

        if (t >= tmask) {                         // wave-uniform (last 2 tiles)
            const int kt = t * 32;
#pragma unroll
            for (int r = 0; r < 16; ++r) {
                const int key = kt + (r & 3) + 8 * (r >> 2) + 4 * hi;
                S[r] = (key <= qv16) ? S[r] : -INFINITY;
            }
        }
        unsigned pk[8];
#pragma unroll
        for (int j = 0; j < 8; ++j) {
            const float p0 = __builtin_amdgcn_exp2f(S[2 * j]);
            const float p1 = __builtin_amdgcn_exp2f(S[2 * j + 1]);
            lsum += p0 + p1;
            asm("v_cvt_pk_bf16_f32 %0, %1, %2" : "=v"(pk[j]) : "v"(p0), "v"(p1));
        }
        // relayout via permlane32_swap (verified R6: absmax unchanged)
        unsigned a0 = pk[0], a2 = pk[2];
        unsigned a1 = pk[1], a3 = pk[3];
        unsigned a4 = pk[4], a6 = pk[6];
        unsigned a5 = pk[5], a7 = pk[7];
        asm("v_permlane32_swap_b32 %0, %1" : "+v"(a0), "+v"(a2));
        asm("v_permlane32_swap_b32 %0, %1" : "+v"(a1), "+v"(a3));
        asm("v_permlane32_swap_b32 %0, %1" : "+v"(a4), "+v"(a6));
        asm("v_permlane32_swap_b32 %0, %1" : "+v"(a5), "+v"(a7));
        union { unsigned u[4]; short8 v; } b1, b2;
        b1.u[0] = a0; b1.u[1] = a1; b1.u[2] = a2; b1.u[3] = a3;
        b2.u[0] = a4; b2.u[1] = a5; b2.u[2] = a6; b2.u[3] = a7;

        acc = __builtin_amdgcn_mfma_f32_32x32x16_bf16(va, b1.v, acc, 0, 0, 0);
        acc = __builtin_amdgcn_mfma_f32_32x32x16_bf16(vv, b2.v, acc, 0, 0, 0);
        kf = kf_n; va = va_n; vv = vv_n;
    }

    // acc regs 0..7 hold O-partial[dv = (r&3)+8*(r>>2)+4*hi][q = q0+qc]
    uint4v pa;
    asm("v_cvt_pk_bf16_f32 %0, %1, %2" : "=v"(pa.x) : "v"(acc[0]), "v"(acc[1]));
    asm("v_cvt_pk_bf16_f32 %0, %1, %2" : "=v"(pa.y) : "v"(acc[2]), "v"(acc[3]));
    asm("v_cvt_pk_bf16_f32 %0, %1, %2" : "=v"(pa.z) : "v"(acc[4]), "v"(acc[5]));
    asm("v_cvt_pk_bf16_f32 %0, %1, %2" : "=v"(pa.w) : "v"(acc[6]), "v"(acc[7]));

    const int pidx = (bh * 64 + qt) * MAXSP + sp;
    *(uint4v*)(PartA + ((size_t)pidx * 64 + lane) * 4) = pa;

    lsum += __shfl_xor(lsum, 32);     // combine hi halves: full row sum for qc
    if (hi == 0) PartL[(size_t)pidx * 32 + qc] = lsum;
}

// ---------------------------------------------------------------------------
// attn_combine: wave per (bh,qt): sum <=MAXSP partials, normalize, write Z.
// ---------------------------------------------------------------------------
__global__ __launch_bounds__(256) void attn_combine(
    const unsigned* __restrict__ PartA, const float* __restrict__ PartL,
    short* __restrict__ Zb)
{
    const int w    = threadIdx.x >> 6;
    const int lane = threadIdx.x & 63;
    const int wid  = blockIdx.x * 4 + w;     // 0..2047
    const int bh   = wid >> 6;
    const int qt   = wid & 63;
    const int hi   = lane >> 5;
    const int qc   = lane & 31;
    const int ns   = (qt + 2 + TSPLIT - 1) / TSPLIT;

    float a[8];
#pragma unroll
    for (int r = 0; r < 8; ++r) a[r] = 0.f;
    float lsum = 0.f;

    const int pbase = (bh * 64 + qt) * MAXSP;
    for (int sp = 0; sp < ns; ++sp) {
        uint4v pa = *(const uint4v*)(PartA + ((size_t)(pbase + sp) * 64 + lane) * 4);
        a[0] += frombf_lo(pa.x); a[1] += frombf_hi(pa.x);
        a[2] += frombf_lo(pa.y); a[3] += frombf_hi(pa.y);
        a[4] += frombf_lo(pa.z); a[5] += frombf_hi(pa.z);
        a[6] += frombf_lo(pa.w); a[7] += frombf_hi(pa.w);
        lsum += PartL[(size_t)(pbase + sp) * 32 + qc];
    }
    const float inv = 1.f / lsum;

    const int b = bh >> 4, h = bh & 15;
    const int q0 = qt * 32;
    short* zp = Zb + ((size_t)(b * S_ + q0 + qc)) * C_ + h * 16;
    unsigned o01, o23, o45, o67;
    {
        float a0 = a[0] * inv, a1 = a[1] * inv, a2 = a[2] * inv, a3 = a[3] * inv;
        float a4 = a[4] * inv, a5 = a[5] * inv, a6 = a[6] * inv, a7 = a[7] * inv;
        asm("v_cvt_pk_bf16_f32 %0, %1, %2" : "=v"(o01) : "v"(a0), "v"(a1));
        asm("v_cvt_pk_bf16_f32 %0, %1, %2" : "=v"(o23) : "v"(a2), "v"(a3));
        asm("v_cvt_pk_bf16_f32 %0, %1, %2" : "=v"(o45) : "v"(a4), "v"(a5));
        asm("v_cvt_pk_bf16_f32 %0, %1, %2" : "=v"(o67) : "v"(a6), "v"(a7));
    }
    *(unsigned*)(zp + 4 * hi)         = o01;
    *(unsigned*)(zp + 4 * hi + 2)     = o23;
    *(unsigned*)(zp + 8 + 4 * hi)     = o45;
    *(unsigned*)(zp + 8 + 4 * hi + 2) = o67;
}

extern "C" void kernel_launch(void* const* d_in, const int* in_sizes, int n_in,
                              void* d_out, int out_size, void* d_ws, size_t ws_size,
                              hipStream_t stream)
{
    const float* resid = (const float*)d_in[0];
    const float* WQ = (const float*)d_in[1];
    const float* WK = (const float*)d_in[2];
    const float* WV = (const float*)d_in[3];
    const float* WO = (const float*)d_in[4];
    const float* bQ = (const float*)d_in[5];
    const float* bK = (const float*)d_in[6];
    const float* bV = (const float*)d_in[7];
    const float* bO = (const float*)d_in[8];
    const float* vK = (const float*)d_in[9];
    const float* vV = (const float*)d_in[10];
    float* out = (float*)d_out;
    float* ws  = (float*)d_ws;

    float* P    = ws;                               // 3,145,728 f32
    float* bqkv = ws + 3145728;                     // 768 f32
    short* Ab   = (short*)(ws + 3145728 + 768);     // 3,145,728 bf16
    short* Wqt  = Ab + 3145728;                     // 589,824
    short* WtO  = Wqt + 589824;                     // 196,608
    short* Qb2  = WtO + 196608;                     // 32*64*512  = 1,048,576
    short* Kb2  = Qb2 + 1048576;                    // 32*65*512  = 1,064,960
    short* Vt3  = Kb2 + 1064960;                    // 32*65*1024 = 2,129,920
    unsigned* PartA = (unsigned*)(Vt3 + 2129920);   // 10240*64*4 u32 = 10.5 MB
    float*    PartL = (float*)(PartA + 2621440);    // 10240*32 f32
    short* Zb   = (short*)ws;                       // aliases P (dead after rope)

    conv_bf16<<<dim3(3072), 256, 0, stream>>>(resid, Ab, 4096 * 768);
    conv_weights<<<dim3(3075), 256, 0, stream>>>(WQ, WK, WV, WO, bQ, bK, bV,
                                                 Wqt, bqkv, WtO);
    mm_mfma<768><<<dim3(12, 32), 256, 0, stream>>>(Ab, Wqt, bqkv, P);
    rope_scatter2<<<dim3((32 * SKP + 255) / 256), 256, 0, stream>>>(P, vK, vV, Qb2, Kb2, Vt3);
    attn_split<<<dim3(32 * 64 * MAXSP / 4), 256, 0, stream>>>(Qb2, Kb2, Vt3, PartA, PartL);
    attn_combine<<<dim3(512), 256, 0, stream>>>(PartA, PartL, Zb);
    mm_mfma<256><<<dim3(12, 32), 256, 0, stream>>>(Zb, WtO, bO, out);
}

// Round 8
// 60.911 us; speedup vs baseline: 7.2234x; 1.3045x over previous
//
#include <hip/hip_runtime.h>
#include <hip/hip_bf16.h>
#include <math.h>

// Problem constants
#define B_   2
#define S_   2048
#define DM   768
#define H_   16      // N_QK
#define C_   256     // N_OV
#define VKV_ 16
#define SK   2064    // S_ + VKV_
#define SKP  2080
#define NT_  65      // key tiles per bh

#define TSPLIT 16
#define MAXSP  5     // ceil(65/16)
#define NACT   164   // active (qt,sp) pairs per bh

typedef __attribute__((ext_vector_type(8))) short short8;    // 8 bf16
typedef __attribute__((ext_vector_type(4))) short short4v;
typedef __attribute__((ext_vector_type(4))) float f32x4;
typedef __attribute__((ext_vector_type(16))) float f32x16;
typedef __attribute__((ext_vector_type(4))) unsigned uint4v;

// log2(e) / SCALE folded into Q so p = exp2(s)
#define QSCALE 0.360673760222240851f
// log2(10000)/8
#define L2B8   1.6609640474436811f

__device__ __forceinline__ short tobf(float f) {
    union { float f; unsigned u; } x; x.f = f;
    unsigned r = x.u + 0x7FFFu + ((x.u >> 16) & 1u);   // RNE
    return (short)(r >> 16);
}
__device__ __forceinline__ float frombf_lo(unsigned u) {
    union { unsigned u; float f; } x; x.u = u << 16; return x.f;
}
__device__ __forceinline__ float frombf_hi(unsigned u) {
    union { unsigned u; float f; } x; x.u = u & 0xFFFF0000u; return x.f;
}

__device__ __forceinline__ void gload_lds16(const short* g, short* l) {
    __builtin_amdgcn_global_load_lds(
        (const __attribute__((address_space(1))) unsigned int*)g,
        (__attribute__((address_space(3))) unsigned int*)l, 16, 0, 0);
}

// ---------------------------------------------------------------------------
// conv_all: resid->bf16, weights pack, bias pack, K/V tail (s>=2048) init.
// ---------------------------------------------------------------------------
#define NRES (4096*768/4)
#define NWQ  (768*768)
#define NWO  (768*256)
__global__ __launch_bounds__(256) void conv_all(
    const float* __restrict__ resid,
    const float* __restrict__ WQ, const float* __restrict__ WK,
    const float* __restrict__ WV, const float* __restrict__ WO,
    const float* __restrict__ bQ, const float* __restrict__ bK,
    const float* __restrict__ bV,
    const float* __restrict__ vKp, const float* __restrict__ vVp,
    short* __restrict__ Ab, short* __restrict__ Wqkv_t,
    short* __restrict__ WtO, float* __restrict__ bqkv,
    short* __restrict__ Kb2, short* __restrict__ Vt3)
{
    int t = blockIdx.x * 256 + threadIdx.x;
    if (t < NRES) {
        float4 v = *(const float4*)(resid + (size_t)t * 4);
        short4v o = { tobf(v.x), tobf(v.y), tobf(v.z), tobf(v.w) };
        *(short4v*)(Ab + (size_t)t * 4) = o;
        return;
    }
    t -= NRES;
    if (t < NWQ) {
        int cc = t / 768, d = t % 768;
        float w;
        if (cc < 256)      w = WQ[((size_t)(cc >> 4) * DM + d) * 16 + (cc & 15)];
        else if (cc < 512) w = WK[((size_t)((cc - 256) >> 4) * DM + d) * 16 + (cc & 15)];
        else               w = WV[(size_t)(cc - 512) * DM + d];
        Wqkv_t[t] = tobf(w);
        return;
    }
    t -= NWQ;
    if (t < NWO) {
        int c = t & 255, m = t >> 8;
        WtO[t] = tobf(WO[(size_t)c * DM + m]);
        return;
    }
    t -= NWO;
    if (t < 768) {
        bqkv[t] = (t < 256) ? bQ[t] : (t < 512 ? bK[t - 256] : bV[t - 512]);
        return;
    }
    t -= 768;
    if (t < 32 * 32) {               // tails: s in [2048, 2080)
        const int bh = t >> 5;
        const int s  = S_ + (t & 31);
        const int h  = bh & 15;
        short kb[16], vb[16];
        if (s < SK) {
            const int tt = s - S_;
#pragma unroll
            for (int e = 0; e < 16; ++e) {
                kb[e] = tobf(vKp[(size_t)tt * 256 + h * 16 + e]);
                vb[e] = tobf(vVp[(size_t)tt * 256 + h * 16 + e]);
            }
        } else {
#pragma unroll
            for (int e = 0; e < 16; ++e) { kb[e] = 0; vb[e] = 0; }
        }
        const int t5 = s >> 5;       // == 64
        short* kbase = Kb2 + ((size_t)bh * NT_ + t5) * 512 + (s & 31) * 8;
#pragma unroll
        for (int e = 0; e < 8; ++e)  { kbase[e] = kb[e]; kbase[256 + e] = kb[e + 8]; }
        short* vbase = Vt3 + ((size_t)bh * NT_ + t5) * 1024
                     + ((s >> 4) & 1) * 512 + ((s >> 3) & 1) * 8 + (s & 7);
#pragma unroll
        for (int dv = 0; dv < 16; ++dv) vbase[dv * 16] = vb[dv];
    }
}

// ---------------------------------------------------------------------------
// mm_qkv: C = A[4096][768] * Wqkv_t^T + bqkv, with FUSED rotary + scatter
//  epilogue writing Qb2/Kb2/Vt3 directly (no P round-trip).
//  Region is block-uniform: n0<256 Q, <512 K, else V.
// ---------------------------------------------------------------------------
__global__ __launch_bounds__(256) void mm_qkv(
    const short* __restrict__ A, const short* __restrict__ Bt,
    const float* __restrict__ bias,
    short* __restrict__ Qb2, short* __restrict__ Kb2, short* __restrict__ Vt3)
{
    __shared__ short As[128 * 64];
    __shared__ short Bs[64 * 64];

    const int tid  = threadIdx.x;
    const int w    = tid >> 6;
    const int lane = tid & 63;
    const int wm   = w >> 1, wn = w & 1;
    const int g    = lane >> 4, c = lane & 15;
    const int m0   = blockIdx.y * 128;
    const int n0   = blockIdx.x * 64;

    f32x4 acc[4][2];
#pragma unroll
    for (int i = 0; i < 4; ++i)
#pragma unroll
        for (int j = 0; j < 2; ++j) acc[i][j] = (f32x4){0.f, 0.f, 0.f, 0.f};

    const int lr = lane >> 3;
    const int lc = lane & 7;

    for (int k0 = 0; k0 < 768; k0 += 64) {
#pragma unroll
        for (int i = 0; i < 4; ++i) {
            const int ch  = i * 4 + w;
            const int row = ch * 8 + lr;
            const int scc = lc ^ (row & 7);
            gload_lds16(A + (size_t)(m0 + row) * 768 + k0 + scc * 8, As + ch * 512);
        }
#pragma unroll
        for (int i = 0; i < 2; ++i) {
            const int ch  = i * 4 + w;
            const int row = ch * 8 + lr;
            const int scc = lc ^ (row & 7);
            gload_lds16(Bt + (size_t)(n0 + row) * 768 + k0 + scc * 8, Bs + ch * 512);
        }
        __syncthreads();
#pragma unroll
        for (int kk = 0; kk < 64; kk += 32) {
            short8 af[4], bf[2];
#pragma unroll
            for (int i = 0; i < 4; ++i) {
                const int row = wm * 64 + i * 16 + c;
                const int sc  = ((kk >> 3) + g) ^ (row & 7);
                af[i] = *(const short8*)(As + row * 64 + sc * 8);
            }
#pragma unroll
            for (int j = 0; j < 2; ++j) {
                const int row = wn * 32 + j * 16 + c;
                const int sc  = ((kk >> 3) + g) ^ (row & 7);
                bf[j] = *(const short8*)(Bs + row * 64 + sc * 8);
            }
#pragma unroll
            for (int i = 0; i < 4; ++i)
#pragma unroll
                for (int j = 0; j < 2; ++j)
                    acc[i][j] = __builtin_amdgcn_mfma_f32_16x16x32_bf16(
                        af[i], bf[j], acc[i][j], 0, 0, 0);
        }
        __syncthreads();
    }

    // ---- fused epilogue ----
    const float bv0 = bias[n0 + wn * 32 + c];
    const float bv1 = bias[n0 + wn * 32 + 16 + c];

    if (n0 < 512) {
        // Q or K region: rotary. e = c (0..15), angle idx ie = c&7.
        const int isQ = (n0 < 256) ? 1 : 0;
        const float invf = __builtin_amdgcn_exp2f(-(float)(c & 7) * L2B8);
        const int h0 = (((n0 + wn * 32) & 255) >> 4);       // head of j=0
        const int elo = (c & 8) ? 0 : 1;                     // e<8 ?
#pragma unroll
        for (int i = 0; i < 4; ++i) {
#pragma unroll
            for (int r = 0; r < 4; ++r) {
                const int row = m0 + wm * 64 + i * 16 + 4 * g + r;
                const int s   = row & 2047;
                const int b   = row >> 11;
                float sn, cs;
                __sincosf((float)s * invf, &sn, &cs);
#pragma unroll
                for (int j = 0; j < 2; ++j) {
                    float val = acc[i][j][r] + (j ? bv1 : bv0);
                    float par = __shfl_xor(val, 8);
                    float rot = elo ? -par : par;
                    float out = val * cs + rot * sn;
                    if (isQ) out *= QSCALE;
                    const int bh = b * 16 + h0 + j;
                    const size_t base = isQ
                        ? ((size_t)bh * 64 + (s >> 5)) * 512
                        : (size_t)4 * 1024 * 1024 * 0 + ((size_t)bh * NT_ + (s >> 5)) * 512;
                    short* dst = (isQ ? Qb2 : Kb2) + base
                               + (s & 31) * 8 + (c >> 3) * 256 + (c & 7);
                    *dst = tobf(out);
                }
            }
        }
    } else {
        // V region: dv = c, head pair from cols.
        const int h0 = ((n0 + wn * 32 - 512) >> 4);
#pragma unroll
        for (int i = 0; i < 4; ++i) {
#pragma unroll
            for (int r = 0; r < 4; ++r) {
                const int row = m0 + wm * 64 + i * 16 + 4 * g + r;
                const int s   = row & 2047;
                const int b   = row >> 11;
#pragma unroll
                for (int j = 0; j < 2; ++j) {
                    float val = acc[i][j][r] + (j ? bv1 : bv0);
                    const int bh = b * 16 + h0 + j;
                    short* dst = Vt3 + ((size_t)bh * NT_ + (s >> 5)) * 1024
                               + ((s >> 4) & 1) * 512 + ((s >> 3) & 1) * 8 + (s & 7)
                               + c * 16;
                    *dst = tobf(val);
                }
            }
        }
    }
}

// ---------------------------------------------------------------------------
// mm_out: out[4096][768] = Zb[4096][256] * WtO^T + bO  (fp32 out)
// ---------------------------------------------------------------------------
__global__ __launch_bounds__(256) void mm_out(
    const short* __restrict__ A, const short* __restrict__ Bt,
    const float* __restrict__ bias, float* __restrict__ Cout)
{
    __shared__ short As[128 * 64];
    __shared__ short Bs[64 * 64];

    const int tid  = threadIdx.x;
    const int w    = tid >> 6;
    const int lane = tid & 63;
    const int wm   = w >> 1, wn = w & 1;
    const int g    = lane >> 4, c = lane & 15;
    const int m0   = blockIdx.y * 128;
    const int n0   = blockIdx.x * 64;

    f32x4 acc[4][2];
#pragma unroll
    for (int i = 0; i < 4; ++i)
#pragma unroll
        for (int j = 0; j < 2; ++j) acc[i][j] = (f32x4){0.f, 0.f, 0.f, 0.f};

    const int lr = lane >> 3;
    const int lc = lane & 7;

    for (int k0 = 0; k0 < 256; k0 += 64) {
#pragma unroll
        for (int i = 0; i < 4; ++i) {
            const int ch  = i * 4 + w;
            const int row = ch * 8 + lr;
            const int scc = lc ^ (row & 7);
            gload_lds16(A + (size_t)(m0 + row) * 256 + k0 + scc * 8, As + ch * 512);
        }
#pragma unroll
        for (int i = 0; i < 2; ++i) {
            const int ch  = i * 4 + w;
            const int row = ch * 8 + lr;
            const int scc = lc ^ (row & 7);
            gload_lds16(Bt + (size_t)(n0 + row) * 256 + k0 + scc * 8, Bs + ch * 512);
        }
        __syncthreads();
#pragma unroll
        for (int kk = 0; kk < 64; kk += 32) {
            short8 af[4], bf[2];
#pragma unroll
            for (int i = 0; i < 4; ++i) {
                const int row = wm * 64 + i * 16 + c;
                const int sc  = ((kk >> 3) + g) ^ (row & 7);
                af[i] = *(const short8*)(As + row * 64 + sc * 8);
            }
#pragma unroll
            for (int j = 0; j < 2; ++j) {
                const int row = wn * 32 + j * 16 + c;
                const int sc  = ((kk >> 3) + g) ^ (row & 7);
                bf[j] = *(const short8*)(Bs + row * 64 + sc * 8);
            }
#pragma unroll
            for (int i = 0; i < 4; ++i)
#pragma unroll
                for (int j = 0; j < 2; ++j)
                    acc[i][j] = __builtin_amdgcn_mfma_f32_16x16x32_bf16(
                        af[i], bf[j], acc[i][j], 0, 0, 0);
        }
        __syncthreads();
    }
#pragma unroll
    for (int i = 0; i < 4; ++i)
#pragma unroll
        for (int j = 0; j < 2; ++j) {
            const int col = n0 + wn * 32 + j * 16 + c;
            const float bv = bias[col];
#pragma unroll
            for (int r = 0; r < 4; ++r) {
                const int row = m0 + wm * 64 + i * 16 + 4 * g + r;
                Cout[(size_t)row * DM + col] = acc[i][j][r] + bv;
            }
        }
}

// ---------------------------------------------------------------------------
// attn_split: 32x32x16-MFMA, no max tracking, key-split, PAIRED tile loop
//  (2 independent key-tiles interleaved for ILP) + next-pair prefetch.
//  Compact wave mapping: all 5248 waves active, long splits dispatch first.
// ---------------------------------------------------------------------------
__global__ __launch_bounds__(256) void attn_split(
    const short* __restrict__ Qb2, const short* __restrict__ Kb2,
    const short* __restrict__ Vt3, unsigned* __restrict__ PartA,
    float* __restrict__ PartL)
{
    const int w    = threadIdx.x >> 6;
    const int lane = threadIdx.x & 63;
    const int wid  = blockIdx.x * 4 + w;          // 0..5247
    const int bh   = wid / NACT;
    const int r    = wid - bh * NACT;
    int qt, sp;
    if (r < 49)       { sp = 1; qt = 15 + r; }
    else if (r < 82)  { sp = 2; qt = 31 + (r - 49); }
    else if (r < 99)  { sp = 3; qt = 47 + (r - 82); }
    else if (r == 99) { sp = 4; qt = 63; }
    else              { sp = 0; qt = 163 - r; }

    const int nt   = qt + 2;
    const int t0   = sp * TSPLIT;
    const int tend = min(t0 + TSPLIT, nt);

    const int hi = lane >> 5;
    const int qc = lane & 31;
    const int q0 = qt * 32;

    const f32x16 zero16 = {0,0,0,0,0,0,0,0,0,0,0,0,0,0,0,0};

    short8 qf = *(const short8*)(Qb2 + ((size_t)bh * 64 + qt) * 512 + lane * 8);

    f32x16 acc = zero16;
    float lsum = 0.f;

    const short* kbase = Kb2 + (size_t)bh * NT_ * 512 + lane * 8;
    const short* vbase = Vt3 + (size_t)bh * NT_ * 1024 + (lane & 15) * 16 + hi * 8;
    const int qv16  = q0 + qc + 16;
    const int tmask = (q0 + 17) >> 5;      // first tile index needing mask

#define LK(tt)  (*(const short8*)(kbase + (size_t)(tt) * 512))
#define LVA(tt) (*(const short8*)(vbase + (size_t)(tt) * 1024))
#define LVB(tt) (*(const short8*)(vbase + (size_t)(tt) * 1024 + 512))

#define SOFTMAX_TILE(S, tt, B1, B2)                                          \
    {                                                                        \
        if ((tt) >= tmask) {                                                 \
            const int kt_ = (tt) * 32;                                       \
            _Pragma("unroll")                                                \
            for (int rr = 0; rr < 16; ++rr) {                                \
                const int key = kt_ + (rr & 3) + 8 * (rr >> 2) + 4 * hi;     \
                S[rr] = (key <= qv16) ? S[rr] : -INFINITY;                   \
            }                                                                \
        }                                                                    \
        unsigned pk[8];                                                      \
        _Pragma("unroll")                                                    \
        for (int jj = 0; jj < 8; ++jj) {                                     \
            const float p0 = __builtin_amdgcn_exp2f(S[2 * jj]);              \
            const float p1 = __builtin_amdgcn_exp2f(S[2 * jj + 1]);          \
            lsum += p0 + p1;                                                 \
            asm("v_cvt_pk_bf16_f32 %0, %1, %2" : "=v"(pk[jj]) : "v"(p0), "v"(p1)); \
        }                                                                    \
        unsigned a0 = pk[0], a2 = pk[2], a1 = pk[1], a3 = pk[3];             \
        unsigned a4 = pk[4], a6 = pk[6], a5 = pk[5], a7 = pk[7];             \
        asm("v_permlane32_swap_b32 %0, %1" : "+v"(a0), "+v"(a2));            \
        asm("v_permlane32_swap_b32 %0, %1" : "+v"(a1), "+v"(a3));            \
        asm("v_permlane32_swap_b32 %0, %1" : "+v"(a4), "+v"(a6));            \
        asm("v_permlane32_swap_b32 %0, %1" : "+v"(a5), "+v"(a7));            \
        B1.u[0] = a0; B1.u[1] = a1; B1.u[2] = a2; B1.u[3] = a3;              \
        B2.u[0] = a4; B2.u[1] = a5; B2.u[2] = a6; B2.u[3] = a7;              \
    }

    const int npair_end = t0 + ((tend - t0) & ~1);

    if (t0 < npair_end) {
        short8 kfA = LK(t0),     vaA = LVA(t0),     vvA = LVB(t0);
        short8 kfB = LK(t0 + 1), vaB = LVA(t0 + 1), vvB = LVB(t0 + 1);

        for (int t = t0; t < npair_end; t += 2) {
            short8 kfA_n = kfA, vaA_n = vaA, vvA_n = vvA;
            short8 kfB_n = kfB, vaB_n = vaB, vvB_n = vvB;
            if (t + 2 < npair_end) {
                kfA_n = LK(t + 2); vaA_n = LVA(t + 2); vvA_n = LVB(t + 2);
                kfB_n = LK(t + 3); vaB_n = LVA(t + 3); vvB_n = LVB(t + 3);
            }

            f32x16 S0 = __builtin_amdgcn_mfma_f32_32x32x16_bf16(kfA, qf, zero16, 0, 0, 0);
            f32x16 S1 = __builtin_amdgcn_mfma_f32_32x32x16_bf16(kfB, qf, zero16, 0, 0, 0);

            union { unsigned u[4]; short8 v; } b1A, b2A, b1B, b2B;
            SOFTMAX_TILE(S0, t,     b1A, b2A);
            SOFTMAX_TILE(S1, t + 1, b1B, b2B);

            acc = __builtin_amdgcn_mfma_f32_32x32x16_bf16(vaA, b1A.v, acc, 0, 0, 0);
            acc = __builtin_amdgcn_mfma_f32_32x32x16_bf16(vvA, b2A.v, acc, 0, 0, 0);
            acc = __builtin_amdgcn_mfma_f32_32x32x16_bf16(vaB, b1B.v, acc, 0, 0, 0);
            acc = __builtin_amdgcn_mfma_f32_32x32x16_bf16(vvB, b2B.v, acc, 0, 0, 0);

            kfA = kfA_n; vaA = vaA_n; vvA = vvA_n;
            kfB = kfB_n; vaB = vaB_n; vvB = vvB_n;
        }
    }
    if (npair_end < tend) {                        // odd tail tile
        const int t = npair_end;
        short8 kf = LK(t), va = LVA(t), vv = LVB(t);
        f32x16 S0 = __builtin_amdgcn_mfma_f32_32x32x16_bf16(kf, qf, zero16, 0, 0, 0);
        union { unsigned u[4]; short8 v; } b1, b2;
        SOFTMAX_TILE(S0, t, b1, b2);
        acc = __builtin_amdgcn_mfma_f32_32x32x16_bf16(va, b1.v, acc, 0, 0, 0);
        acc = __builtin_amdgcn_mfma_f32_32x32x16_bf16(vv, b2.v, acc, 0, 0, 0);
    }

    uint4v pa;
    asm("v_cvt_pk_bf16_f32 %0, %1, %2" : "=v"(pa.x) : "v"(acc[0]), "v"(acc[1]));
    asm("v_cvt_pk_bf16_f32 %0, %1, %2" : "=v"(pa.y) : "v"(acc[2]), "v"(acc[3]));
    asm("v_cvt_pk_bf16_f32 %0, %1, %2" : "=v"(pa.z) : "v"(acc[4]), "v"(acc[5]));
    asm("v_cvt_pk_bf16_f32 %0, %1, %2" : "=v"(pa.w) : "v"(acc[6]), "v"(acc[7]));

    const int pidx = (bh * 64 + qt) * MAXSP + sp;
    *(uint4v*)(PartA + ((size_t)pidx * 64 + lane) * 4) = pa;

    lsum += __shfl_xor(lsum, 32);
    if (hi == 0) PartL[(size_t)pidx * 32 + qc] = lsum;
}

// ---------------------------------------------------------------------------
// attn_combine: wave per (bh,qt): sum <=MAXSP partials, normalize, write Z.
// ---------------------------------------------------------------------------
__global__ __launch_bounds__(256) void attn_combine(
    const unsigned* __restrict__ PartA, const float* __restrict__ PartL,
    short* __restrict__ Zb)
{
    const int w    = threadIdx.x >> 6;
    const int lane = threadIdx.x & 63;
    const int wid  = blockIdx.x * 4 + w;
    const int bh   = wid >> 6;
    const int qt   = wid & 63;
    const int hi   = lane >> 5;
    const int qc   = lane & 31;
    const int ns   = (qt + 2 + TSPLIT - 1) / TSPLIT;

    float a[8];
#pragma unroll
    for (int rr = 0; rr < 8; ++rr) a[rr] = 0.f;
    float lsum = 0.f;

    const int pbase = (bh * 64 + qt) * MAXSP;
    for (int sp = 0; sp < ns; ++sp) {
        uint4v pa = *(const uint4v*)(PartA + ((size_t)(pbase + sp) * 64 + lane) * 4);
        a[0] += frombf_lo(pa.x); a[1] += frombf_hi(pa.x);
        a[2] += frombf_lo(pa.y); a[3] += frombf_hi(pa.y);
        a[4] += frombf_lo(pa.z); a[5] += frombf_hi(pa.z);
        a[6] += frombf_lo(pa.w); a[7] += frombf_hi(pa.w);
        lsum += PartL[(size_t)(pbase + sp) * 32 + qc];
    }
    const float inv = 1.f / lsum;

    const int b = bh >> 4, h = bh & 15;
    const int q0 = qt * 32;
    short* zp = Zb + ((size_t)(b * S_ + q0 + qc)) * C_ + h * 16;
    unsigned o01, o23, o45, o67;
    {
        float a0 = a[0] * inv, a1 = a[1] * inv, a2 = a[2] * inv, a3 = a[3] * inv;
        float a4 = a[4] * inv, a5 = a[5] * inv, a6 = a[6] * inv, a7 = a[7] * inv;
        asm("v_cvt_pk_bf16_f32 %0, %1, %2" : "=v"(o01) : "v"(a0), "v"(a1));
        asm("v_cvt_pk_bf16_f32 %0, %1, %2" : "=v"(o23) : "v"(a2), "v"(a3));
        asm("v_cvt_pk_bf16_f32 %0, %1, %2" : "=v"(o45) : "v"(a4), "v"(a5));
        asm("v_cvt_pk_bf16_f32 %0, %1, %2" : "=v"(o67) : "v"(a6), "v"(a7));
    }
    *(unsigned*)(zp + 4 * hi)         = o01;
    *(unsigned*)(zp + 4 * hi + 2)     = o23;
    *(unsigned*)(zp + 8 + 4 * hi)     = o45;
    *(unsigned*)(zp + 8 + 4 * hi + 2) = o67;
}

extern "C" void kernel_launch(void* const* d_in, const int* in_sizes, int n_in,
                              void* d_out, int out_size, void* d_ws, size_t ws_size,
                              hipStream_t stream)
{
    const float* resid = (const float*)d_in[0];
    const float* WQ = (const float*)d_in[1];
    const float* WK = (const float*)d_in[2];
    const float* WV = (const float*)d_in[3];
    const float* WO = (const float*)d_in[4];
    const float* bQ = (const float*)d_in[5];
    const float* bK = (const float*)d_in[6];
    const float* bV = (const float*)d_in[7];
    const float* bO = (const float*)d_in[8];
    const float* vK = (const float*)d_in[9];
    const float* vV = (const float*)d_in[10];
    float* out = (float*)d_out;
    float* ws  = (float*)d_ws;

    short* Zb   = (short*)ws;                       // 4096*256 bf16
    float* bqkv = ws + 3145728;                     // 768 f32
    short* Ab   = (short*)(ws + 3145728 + 768);     // 3,145,728 bf16
    short* Wqt  = Ab + 3145728;                     // 589,824
    short* WtO  = Wqt + 589824;                     // 196,608
    short* Qb2  = WtO + 196608;                     // 32*64*512  = 1,048,576
    short* Kb2  = Qb2 + 1048576;                    // 32*65*512  = 1,064,960
    short* Vt3  = Kb2 + 1064960;                    // 32*65*1024 = 2,129,920
    unsigned* PartA = (unsigned*)(Vt3 + 2129920);   // 10240*64*4 u32
    float*    PartL = (float*)(PartA + 2621440);    // 10240*32 f32

    const int conv_total = NRES + NWQ + NWO + 768 + 1024;
    conv_all<<<dim3((conv_total + 255) / 256), 256, 0, stream>>>(
        resid, WQ, WK, WV, WO, bQ, bK, bV, vK, vV,
        Ab, Wqt, WtO, bqkv, Kb2, Vt3);
    mm_qkv<<<dim3(12, 32), 256, 0, stream>>>(Ab, Wqt, bqkv, Qb2, Kb2, Vt3);
    attn_split<<<dim3(32 * NACT / 4), 256, 0, stream>>>(Qb2, Kb2, Vt3, PartA, PartL);
    attn_combine<<<dim3(512), 256, 0, stream>>>(PartA, PartL, Zb);
    mm_out<<<dim3(12, 32), 256, 0, stream>>>(Zb, WtO, bO, out);
}